// Round 1
// baseline (1043.175 us; speedup 1.0000x reference)
//
#include <hip/hip_runtime.h>

#define N_NODES   100000
#define N_EDGES   1600000
#define IN_CH     128
#define HID       64
#define N_CLASSES 16
#define N_GRAPHS  64

// ---------------------------------------------------------------- init
// deg = 1.0 (self-loop weight), pooled = 0, cnt = 0
__global__ void k_init(float* __restrict__ deg, float* __restrict__ pooled,
                       float* __restrict__ cnt) {
    int i = blockIdx.x * 256 + threadIdx.x;
    if (i < N_NODES) deg[i] = 1.0f;
    if (i < N_GRAPHS * HID) pooled[i] = 0.0f;
    if (i < N_GRAPHS) cnt[i] = 0.0f;
}

// ---------------------------------------------------------------- degree
__global__ void k_deg(const int* __restrict__ dst, const float* __restrict__ ew,
                      float* __restrict__ deg) {
    int e = blockIdx.x * 256 + threadIdx.x;
    if (e < N_EDGES) atomicAdd(&deg[dst[e]], ew[e]);
}

// deg -> deg^{-1/2} in place (deg >= 1 always due to self loops)
__global__ void k_rsqrt(float* __restrict__ deg) {
    int i = blockIdx.x * 256 + threadIdx.x;
    if (i < N_NODES) deg[i] = 1.0f / sqrtf(deg[i]);
}

// ---------------------------------------------------------------- GEMM
// h[N, HID] = x[N, K] @ W[K, HID]; 16 rows per block, 256 threads,
// each thread computes 4 output elements (rows rq, rq+4, rq+8, rq+12).
template <int K>
__global__ void k_gemm(const float* __restrict__ x, const float* __restrict__ W,
                       float* __restrict__ h) {
    __shared__ float ws[K * HID];
    __shared__ float xs[16 * K];
    const int tid = threadIdx.x;
    const int col = tid & 63;
    const int rq  = tid >> 6;          // 0..3
    const int rowbase = blockIdx.x * 16;

    for (int i = tid; i < K * HID; i += 256) ws[i] = W[i];
    for (int i = tid; i < 16 * K; i += 256) {
        int r = i / K, k = i % K;
        xs[r * K + k] = x[(rowbase + r) * K + k];
    }
    __syncthreads();

    float a0 = 0.f, a1 = 0.f, a2 = 0.f, a3 = 0.f;
#pragma unroll 16
    for (int k = 0; k < K; ++k) {
        float wv = ws[k * HID + col];
        a0 += xs[(rq     ) * K + k] * wv;
        a1 += xs[(rq +  4) * K + k] * wv;
        a2 += xs[(rq +  8) * K + k] * wv;
        a3 += xs[(rq + 12) * K + k] * wv;
    }
    h[(rowbase + rq     ) * HID + col] = a0;
    h[(rowbase + rq +  4) * HID + col] = a1;
    h[(rowbase + rq +  8) * HID + col] = a2;
    h[(rowbase + rq + 12) * HID + col] = a3;
}

// ---------------------------------------------------------------- self-loop init
// agg[i, c] = dis[i]^2 * h[i, c]
__global__ void k_selfinit(const float* __restrict__ h, const float* __restrict__ dis,
                           float* __restrict__ agg) {
    int i = blockIdx.x * 256 + threadIdx.x;
    if (i < N_NODES * HID) {
        int node = i >> 6;
        float d = dis[node];
        agg[i] = d * d * h[i];
    }
}

// ---------------------------------------------------------------- edge scatter
// one 64-lane group per edge; lane = channel
__global__ void k_scatter(const int* __restrict__ src, const int* __restrict__ dst,
                          const float* __restrict__ ew, const float* __restrict__ dis,
                          const float* __restrict__ h, float* __restrict__ agg) {
    const int tid = threadIdx.x;
    const int c = tid & 63;
    const int e = blockIdx.x * 4 + (tid >> 6);
    const int s = src[e];
    const int d = dst[e];
    const float norm = dis[s] * ew[e] * dis[d];
    atomicAdd(&agg[d * HID + c], norm * h[s * HID + c]);
}

// ---------------------------------------------------------------- bias + relu
__global__ void k_biasrelu(float* __restrict__ agg, const float* __restrict__ b) {
    int i = blockIdx.x * 256 + threadIdx.x;
    if (i < N_NODES * HID) {
        int c = i & 63;
        agg[i] = fmaxf(agg[i] + b[c], 0.0f);
    }
}

// ---------------------------------------------------------------- pool (fused bias2+relu)
// batch is sorted -> run-length accumulate per thread, few atomics.
#define POOL_NPT 16
__global__ void k_pool(const float* __restrict__ agg, const float* __restrict__ b,
                       const int* __restrict__ batch, float* __restrict__ pooled,
                       float* __restrict__ cnt) {
    const int tid = threadIdx.x;
    const int c = tid & 63;
    const int rq = tid >> 6;  // 0..3
    const int nodebase = (blockIdx.x * 4 + rq) * POOL_NPT;
    const float bc = b[c];

    int curg = -1;
    float accv = 0.f, cntacc = 0.f;
    for (int j = 0; j < POOL_NPT; ++j) {
        int node = nodebase + j;
        if (node >= N_NODES) break;
        int g = batch[node];                       // wave-uniform
        float v = fmaxf(agg[node * HID + c] + bc, 0.0f);
        if (g != curg) {
            if (curg >= 0) {
                atomicAdd(&pooled[curg * HID + c], accv);
                if (c == 0) atomicAdd(&cnt[curg], cntacc);
            }
            curg = g; accv = 0.f; cntacc = 0.f;
        }
        accv += v;
        cntacc += 1.f;
    }
    if (curg >= 0) {
        atomicAdd(&pooled[curg * HID + c], accv);
        if (c == 0) atomicAdd(&cnt[curg], cntacc);
    }
}

// ---------------------------------------------------------------- head
// out[g, k] = (1/max(cnt,1)) * sum_h pooled[g,h] * Wl[h,k] + bl[k]
__global__ void k_out(const float* __restrict__ pooled, const float* __restrict__ cnt,
                      const float* __restrict__ Wl, const float* __restrict__ bl,
                      float* __restrict__ out) {
    int tid = threadIdx.x;              // 1024 threads
    int g = tid >> 4, k = tid & 15;
    float inv = 1.0f / fmaxf(cnt[g], 1.0f);
    float acc = 0.f;
#pragma unroll
    for (int h = 0; h < HID; ++h) acc += pooled[g * HID + h] * Wl[h * N_CLASSES + k];
    out[g * N_CLASSES + k] = acc * inv + bl[k];
}

extern "C" void kernel_launch(void* const* d_in, const int* in_sizes, int n_in,
                              void* d_out, int out_size, void* d_ws, size_t ws_size,
                              hipStream_t stream) {
    const float* x     = (const float*)d_in[0];
    const int*   ei    = (const int*)d_in[1];
    const float* ew    = (const float*)d_in[2];
    const int*   batch = (const int*)d_in[3];
    const float* W1    = (const float*)d_in[4];
    const float* b1    = (const float*)d_in[5];
    const float* W2    = (const float*)d_in[6];
    const float* b2    = (const float*)d_in[7];
    const float* Wl    = (const float*)d_in[8];
    const float* bl    = (const float*)d_in[9];

    const int* srcv = ei;            // edge_index[0]
    const int* dstv = ei + N_EDGES;  // edge_index[1]

    float* ws     = (float*)d_ws;
    float* deg    = ws;                          // N_NODES (holds dis after k_rsqrt)
    float* h      = ws + 131072;                 // N_NODES*HID
    float* agg    = h + N_NODES * HID;           // N_NODES*HID
    float* pooled = agg + N_NODES * HID;         // N_GRAPHS*HID
    float* cnt    = pooled + N_GRAPHS * HID;     // N_GRAPHS
    float* out    = (float*)d_out;

    // norms
    k_init<<<(N_NODES + 255) / 256, 256, 0, stream>>>(deg, pooled, cnt);
    k_deg<<<(N_EDGES + 255) / 256, 256, 0, stream>>>(dstv, ew, deg);
    k_rsqrt<<<(N_NODES + 255) / 256, 256, 0, stream>>>(deg);

    // layer 1
    k_gemm<IN_CH><<<N_NODES / 16, 256, 0, stream>>>(x, W1, h);
    k_selfinit<<<(N_NODES * HID) / 256, 256, 0, stream>>>(h, deg, agg);
    k_scatter<<<N_EDGES / 4, 256, 0, stream>>>(srcv, dstv, ew, deg, h, agg);
    k_biasrelu<<<(N_NODES * HID) / 256, 256, 0, stream>>>(agg, b1);

    // layer 2 (reuse h/agg buffers; stream order makes this safe)
    k_gemm<HID><<<N_NODES / 16, 256, 0, stream>>>(agg, W2, h);
    k_selfinit<<<(N_NODES * HID) / 256, 256, 0, stream>>>(h, deg, agg);
    k_scatter<<<N_EDGES / 4, 256, 0, stream>>>(srcv, dstv, ew, deg, h, agg);

    // pool (fused bias2 + relu) + head
    k_pool<<<(N_NODES + 4 * POOL_NPT - 1) / (4 * POOL_NPT), 256, 0, stream>>>(
        agg, b2, batch, pooled, cnt);
    k_out<<<1, N_GRAPHS * N_CLASSES, 0, stream>>>(pooled, cnt, Wl, bl, out);
}

// Round 2
// 898.306 us; speedup vs baseline: 1.1613x; 1.1613x over previous
//
#include <hip/hip_runtime.h>

#define N_NODES   100000
#define N_EDGES   1600000
#define IN_CH     128
#define HID       64
#define N_CLASSES 16
#define N_GRAPHS  64

// ---------------------------------------------------------------- init
// deg = 1.0 (self-loop weight), count = 0, pooled = 0, cnt = 0
__global__ void k_init(float* __restrict__ deg, int* __restrict__ count,
                       float* __restrict__ pooled, float* __restrict__ cnt) {
    int i = blockIdx.x * 256 + threadIdx.x;
    if (i < N_NODES) { deg[i] = 1.0f; count[i] = 0; }
    if (i < N_GRAPHS * HID) pooled[i] = 0.0f;
    if (i < N_GRAPHS) cnt[i] = 0.0f;
}

// ---------------------------------------------------------------- degree + count
__global__ void k_degcount(const int* __restrict__ dst, const float* __restrict__ ew,
                           float* __restrict__ deg, int* __restrict__ count) {
    int e = blockIdx.x * 256 + threadIdx.x;
    if (e < N_EDGES) {
        int d = dst[e];
        atomicAdd(&deg[d], ew[e]);
        atomicAdd(&count[d], 1);
    }
}

// deg -> deg^{-1/2} in place (deg >= 1 always due to self loops)
__global__ void k_rsqrt(float* __restrict__ deg) {
    int i = blockIdx.x * 256 + threadIdx.x;
    if (i < N_NODES) deg[i] = 1.0f / sqrtf(deg[i]);
}

// ---------------------------------------------------------------- scan (single block)
// rowptr = exclusive prefix sum of count; cursor = copy of rowptr
#define SCAN_CHUNK 98  // 1024 * 98 >= 100000
__global__ void k_scan(const int* __restrict__ count, int* __restrict__ rowptr,
                       int* __restrict__ cursor) {
    __shared__ int part[1024];
    const int tid = threadIdx.x;
    const int beg = tid * SCAN_CHUNK;
    const int end = min(beg + SCAN_CHUNK, N_NODES);
    int s = 0;
    for (int i = beg; i < end; ++i) s += count[i];
    part[tid] = s;
    __syncthreads();
    for (int off = 1; off < 1024; off <<= 1) {
        int v = part[tid];
        int add = (tid >= off) ? part[tid - off] : 0;
        __syncthreads();
        part[tid] = v + add;
        __syncthreads();
    }
    int prefix = (tid == 0) ? 0 : part[tid - 1];
    for (int i = beg; i < end; ++i) {
        rowptr[i] = prefix;
        cursor[i] = prefix;
        prefix += count[i];
    }
    if (tid == 1023) rowptr[N_NODES] = part[1023];
}

// ---------------------------------------------------------------- fill CSR
// csr_src[pos] = src, csr_norm[pos] = dis[src]*ew*dis[dst]
__global__ void k_fill(const int* __restrict__ src, const int* __restrict__ dst,
                       const float* __restrict__ ew, const float* __restrict__ dis,
                       int* __restrict__ cursor, int* __restrict__ csr_src,
                       float* __restrict__ csr_norm) {
    int e = blockIdx.x * 256 + threadIdx.x;
    if (e < N_EDGES) {
        int s = src[e], d = dst[e];
        float nm = dis[s] * ew[e] * dis[d];
        int pos = atomicAdd(&cursor[d], 1);
        csr_src[pos] = s;
        csr_norm[pos] = nm;
    }
}

// ---------------------------------------------------------------- GEMM
// h[N, HID] = x[N, K] @ W[K, HID]; 16 rows per block, 256 threads.
template <int K>
__global__ void k_gemm(const float* __restrict__ x, const float* __restrict__ W,
                       float* __restrict__ h) {
    __shared__ float ws[K * HID];
    __shared__ float xs[16 * K];
    const int tid = threadIdx.x;
    const int col = tid & 63;
    const int rq  = tid >> 6;          // 0..3
    const int rowbase = blockIdx.x * 16;

    for (int i = tid; i < K * HID; i += 256) ws[i] = W[i];
    for (int i = tid; i < 16 * K; i += 256) {
        int r = i / K, k = i % K;
        xs[r * K + k] = x[(rowbase + r) * K + k];
    }
    __syncthreads();

    float a0 = 0.f, a1 = 0.f, a2 = 0.f, a3 = 0.f;
#pragma unroll 16
    for (int k = 0; k < K; ++k) {
        float wv = ws[k * HID + col];
        a0 += xs[(rq     ) * K + k] * wv;
        a1 += xs[(rq +  4) * K + k] * wv;
        a2 += xs[(rq +  8) * K + k] * wv;
        a3 += xs[(rq + 12) * K + k] * wv;
    }
    h[(rowbase + rq     ) * HID + col] = a0;
    h[(rowbase + rq +  4) * HID + col] = a1;
    h[(rowbase + rq +  8) * HID + col] = a2;
    h[(rowbase + rq + 12) * HID + col] = a3;
}

// ---------------------------------------------------------------- aggregate (gather)
// out[i,c] = relu( dis[i]^2*h[i,c] + sum_{e in CSR[i]} norm[e]*h[src[e],c] + b[c] )
// one 64-lane wave per node, lane = channel.
__global__ void k_aggregate(const int* __restrict__ rowptr, const int* __restrict__ csr_src,
                            const float* __restrict__ csr_norm, const float* __restrict__ h,
                            const float* __restrict__ dis, const float* __restrict__ b,
                            float* __restrict__ out) {
    const int tid = threadIdx.x;
    const int c = tid & 63;
    const int node = blockIdx.x * 4 + (tid >> 6);
    if (node >= N_NODES) return;
    const float d = dis[node];
    float acc = d * d * h[node * HID + c];
    int p = rowptr[node];
    const int end = rowptr[node + 1];
    // unroll by 2 for ILP
    for (; p + 2 <= end; p += 2) {
        int s0 = csr_src[p], s1 = csr_src[p + 1];
        float n0 = csr_norm[p], n1 = csr_norm[p + 1];
        float h0 = h[s0 * HID + c];
        float h1 = h[s1 * HID + c];
        acc += n0 * h0;
        acc += n1 * h1;
    }
    if (p < end) {
        int s0 = csr_src[p];
        acc += csr_norm[p] * h[s0 * HID + c];
    }
    out[node * HID + c] = fmaxf(acc + b[c], 0.0f);
}

// ---------------------------------------------------------------- pool
// batch is sorted -> run-length accumulate per thread, few atomics.
#define POOL_NPT 16
__global__ void k_pool(const float* __restrict__ agg, const int* __restrict__ batch,
                       float* __restrict__ pooled, float* __restrict__ cnt) {
    const int tid = threadIdx.x;
    const int c = tid & 63;
    const int rq = tid >> 6;  // 0..3
    const int nodebase = (blockIdx.x * 4 + rq) * POOL_NPT;

    int curg = -1;
    float accv = 0.f, cntacc = 0.f;
    for (int j = 0; j < POOL_NPT; ++j) {
        int node = nodebase + j;
        if (node >= N_NODES) break;
        int g = batch[node];                       // wave-uniform
        float v = agg[node * HID + c];
        if (g != curg) {
            if (curg >= 0) {
                atomicAdd(&pooled[curg * HID + c], accv);
                if (c == 0) atomicAdd(&cnt[curg], cntacc);
            }
            curg = g; accv = 0.f; cntacc = 0.f;
        }
        accv += v;
        cntacc += 1.f;
    }
    if (curg >= 0) {
        atomicAdd(&pooled[curg * HID + c], accv);
        if (c == 0) atomicAdd(&cnt[curg], cntacc);
    }
}

// ---------------------------------------------------------------- head
__global__ void k_out(const float* __restrict__ pooled, const float* __restrict__ cnt,
                      const float* __restrict__ Wl, const float* __restrict__ bl,
                      float* __restrict__ out) {
    int tid = threadIdx.x;              // 1024 threads
    int g = tid >> 4, k = tid & 15;
    float inv = 1.0f / fmaxf(cnt[g], 1.0f);
    float acc = 0.f;
#pragma unroll
    for (int h = 0; h < HID; ++h) acc += pooled[g * HID + h] * Wl[h * N_CLASSES + k];
    out[g * N_CLASSES + k] = acc * inv + bl[k];
}

extern "C" void kernel_launch(void* const* d_in, const int* in_sizes, int n_in,
                              void* d_out, int out_size, void* d_ws, size_t ws_size,
                              hipStream_t stream) {
    const float* x     = (const float*)d_in[0];
    const int*   ei    = (const int*)d_in[1];
    const float* ew    = (const float*)d_in[2];
    const int*   batch = (const int*)d_in[3];
    const float* W1    = (const float*)d_in[4];
    const float* b1    = (const float*)d_in[5];
    const float* W2    = (const float*)d_in[6];
    const float* b2    = (const float*)d_in[7];
    const float* Wl    = (const float*)d_in[8];
    const float* bl    = (const float*)d_in[9];

    const int* srcv = ei;            // edge_index[0]
    const int* dstv = ei + N_EDGES;  // edge_index[1]

    // workspace layout (4-byte elements)
    char* wsb = (char*)d_ws;
    float* deg      = (float*)wsb;                     wsb += 100352 * 4;   // dis after k_rsqrt
    int*   count    = (int*)wsb;                       wsb += 100352 * 4;
    int*   rowptr   = (int*)wsb;                       wsb += 100352 * 4;   // N+1 used
    int*   cursor   = (int*)wsb;                       wsb += 100352 * 4;
    int*   csr_src  = (int*)wsb;                       wsb += N_EDGES * 4;
    float* csr_norm = (float*)wsb;                     wsb += N_EDGES * 4;
    float* h        = (float*)wsb;                     wsb += N_NODES * HID * 4;
    float* agg      = (float*)wsb;                     wsb += N_NODES * HID * 4;
    float* pooled   = (float*)wsb;                     wsb += N_GRAPHS * HID * 4;
    float* cnt      = (float*)wsb;                     wsb += N_GRAPHS * 4;
    float* out      = (float*)d_out;

    // ---- CSR build (shared by both conv layers)
    k_init<<<(N_NODES + 255) / 256, 256, 0, stream>>>(deg, count, pooled, cnt);
    k_degcount<<<(N_EDGES + 255) / 256, 256, 0, stream>>>(dstv, ew, deg, count);
    k_rsqrt<<<(N_NODES + 255) / 256, 256, 0, stream>>>(deg);
    k_scan<<<1, 1024, 0, stream>>>(count, rowptr, cursor);
    k_fill<<<(N_EDGES + 255) / 256, 256, 0, stream>>>(srcv, dstv, ew, deg,
                                                      cursor, csr_src, csr_norm);

    // ---- layer 1
    k_gemm<IN_CH><<<N_NODES / 16, 256, 0, stream>>>(x, W1, h);
    k_aggregate<<<(N_NODES + 3) / 4, 256, 0, stream>>>(rowptr, csr_src, csr_norm,
                                                       h, deg, b1, agg);
    // ---- layer 2
    k_gemm<HID><<<N_NODES / 16, 256, 0, stream>>>(agg, W2, h);
    k_aggregate<<<(N_NODES + 3) / 4, 256, 0, stream>>>(rowptr, csr_src, csr_norm,
                                                       h, deg, b2, agg);

    // ---- pool + head
    k_pool<<<(N_NODES + 4 * POOL_NPT - 1) / (4 * POOL_NPT), 256, 0, stream>>>(
        agg, batch, pooled, cnt);
    k_out<<<1, N_GRAPHS * N_CLASSES, 0, stream>>>(pooled, cnt, Wl, bl, out);
}

// Round 3
// 665.559 us; speedup vs baseline: 1.5674x; 1.3497x over previous
//
#include <hip/hip_runtime.h>

#define N_NODES   100000
#define N_EDGES   1600000
#define IN_CH     128
#define HID       64
#define N_CLASSES 16
#define N_GRAPHS  64
#define NBLK      ((N_NODES + 255) / 256)   // 391 scan blocks

// ---------------------------------------------------------------- init
// deg = 1.0 (self-loop weight), count = 0, pooled = 0, cnt = 0
__global__ void k_init(float* __restrict__ deg, int* __restrict__ count,
                       float* __restrict__ pooled, float* __restrict__ cnt) {
    int i = blockIdx.x * 256 + threadIdx.x;
    if (i < N_NODES) { deg[i] = 1.0f; count[i] = 0; }
    if (i < N_GRAPHS * HID) pooled[i] = 0.0f;
    if (i < N_GRAPHS) cnt[i] = 0.0f;
}

// ---------------------------------------------------------------- degree + count
__global__ void k_degcount(const int* __restrict__ dst, const float* __restrict__ ew,
                           float* __restrict__ deg, int* __restrict__ count) {
    int e = blockIdx.x * 256 + threadIdx.x;
    if (e < N_EDGES) {
        int d = dst[e];
        atomicAdd(&deg[d], ew[e]);
        atomicAdd(&count[d], 1);
    }
}

// deg -> deg^{-1/2} in place (deg >= 1 always due to self loops)
__global__ void k_rsqrt(float* __restrict__ deg) {
    int i = blockIdx.x * 256 + threadIdx.x;
    if (i < N_NODES) deg[i] = 1.0f / sqrtf(deg[i]);
}

// ---------------------------------------------------------------- hierarchical scan
// pass 1: block-local exclusive scan of count -> rowptr (local), block sum -> bsum
__global__ void k_scan_local(const int* __restrict__ count, int* __restrict__ rowptr,
                             int* __restrict__ bsum) {
    __shared__ int sm[256];
    const int t = threadIdx.x;
    const int i = blockIdx.x * 256 + t;
    int v = (i < N_NODES) ? count[i] : 0;
    sm[t] = v;
    __syncthreads();
    for (int off = 1; off < 256; off <<= 1) {
        int add = (t >= off) ? sm[t - off] : 0;
        __syncthreads();
        sm[t] += add;
        __syncthreads();
    }
    if (i < N_NODES) rowptr[i] = sm[t] - v;   // exclusive
    if (t == 255) bsum[blockIdx.x] = sm[255]; // inclusive total
}

// pass 2: exclusive scan of the 391 block sums (single small block)
__global__ void k_scan_bsum(int* __restrict__ bsum) {
    __shared__ int sm[512];
    const int t = threadIdx.x;
    int v = (t < NBLK) ? bsum[t] : 0;
    sm[t] = v;
    __syncthreads();
    for (int off = 1; off < 512; off <<= 1) {
        int add = (t >= off) ? sm[t - off] : 0;
        __syncthreads();
        sm[t] += add;
        __syncthreads();
    }
    if (t < NBLK) bsum[t] = sm[t] - v;        // exclusive
}

// pass 3: add block offsets; materialize cursor; rowptr[N] = E (known statically)
__global__ void k_scan_add(const int* __restrict__ bsum, int* __restrict__ rowptr,
                           int* __restrict__ cursor) {
    int i = blockIdx.x * 256 + threadIdx.x;
    if (i < N_NODES) {
        int r = rowptr[i] + bsum[i >> 8];
        rowptr[i] = r;
        cursor[i] = r;
    }
    if (i == 0) rowptr[N_NODES] = N_EDGES;
}

// ---------------------------------------------------------------- fill CSR
__global__ void k_fill(const int* __restrict__ src, const int* __restrict__ dst,
                       const float* __restrict__ ew, const float* __restrict__ dis,
                       int* __restrict__ cursor, int* __restrict__ csr_src,
                       float* __restrict__ csr_norm) {
    int e = blockIdx.x * 256 + threadIdx.x;
    if (e < N_EDGES) {
        int s = src[e], d = dst[e];
        float nm = dis[s] * ew[e] * dis[d];
        int pos = atomicAdd(&cursor[d], 1);
        csr_src[pos] = s;
        csr_norm[pos] = nm;
    }
}

// ---------------------------------------------------------------- GEMM
// h[N, HID] = x[N, K] @ W[K, HID]; 16 rows per block, 256 threads.
template <int K>
__global__ void k_gemm(const float* __restrict__ x, const float* __restrict__ W,
                       float* __restrict__ h) {
    __shared__ float ws[K * HID];
    __shared__ float xs[16 * K];
    const int tid = threadIdx.x;
    const int col = tid & 63;
    const int rq  = tid >> 6;          // 0..3
    const int rowbase = blockIdx.x * 16;

    for (int i = tid; i < K * HID; i += 256) ws[i] = W[i];
    for (int i = tid; i < 16 * K; i += 256) {
        int r = i / K, k = i % K;
        xs[r * K + k] = x[(rowbase + r) * K + k];
    }
    __syncthreads();

    float a0 = 0.f, a1 = 0.f, a2 = 0.f, a3 = 0.f;
#pragma unroll 16
    for (int k = 0; k < K; ++k) {
        float wv = ws[k * HID + col];
        a0 += xs[(rq     ) * K + k] * wv;
        a1 += xs[(rq +  4) * K + k] * wv;
        a2 += xs[(rq +  8) * K + k] * wv;
        a3 += xs[(rq + 12) * K + k] * wv;
    }
    h[(rowbase + rq     ) * HID + col] = a0;
    h[(rowbase + rq +  4) * HID + col] = a1;
    h[(rowbase + rq +  8) * HID + col] = a2;
    h[(rowbase + rq + 12) * HID + col] = a3;
}

// ---------------------------------------------------------------- aggregate (gather)
// out[i,c] = relu( dis[i]^2*h[i,c] + sum_{e in CSR[i]} norm[e]*h[src[e],c] + b[c] )
__global__ void k_aggregate(const int* __restrict__ rowptr, const int* __restrict__ csr_src,
                            const float* __restrict__ csr_norm, const float* __restrict__ h,
                            const float* __restrict__ dis, const float* __restrict__ b,
                            float* __restrict__ out) {
    const int tid = threadIdx.x;
    const int c = tid & 63;
    const int node = blockIdx.x * 4 + (tid >> 6);
    if (node >= N_NODES) return;
    const float d = dis[node];
    float acc = d * d * h[node * HID + c];
    int p = rowptr[node];
    const int end = rowptr[node + 1];
    for (; p + 2 <= end; p += 2) {
        int s0 = csr_src[p], s1 = csr_src[p + 1];
        float n0 = csr_norm[p], n1 = csr_norm[p + 1];
        float h0 = h[s0 * HID + c];
        float h1 = h[s1 * HID + c];
        acc += n0 * h0;
        acc += n1 * h1;
    }
    if (p < end) {
        int s0 = csr_src[p];
        acc += csr_norm[p] * h[s0 * HID + c];
    }
    out[node * HID + c] = fmaxf(acc + b[c], 0.0f);
}

// ---------------------------------------------------------------- pool
#define POOL_NPT 16
__global__ void k_pool(const float* __restrict__ agg, const int* __restrict__ batch,
                       float* __restrict__ pooled, float* __restrict__ cnt) {
    const int tid = threadIdx.x;
    const int c = tid & 63;
    const int rq = tid >> 6;  // 0..3
    const int nodebase = (blockIdx.x * 4 + rq) * POOL_NPT;

    int curg = -1;
    float accv = 0.f, cntacc = 0.f;
    for (int j = 0; j < POOL_NPT; ++j) {
        int node = nodebase + j;
        if (node >= N_NODES) break;
        int g = batch[node];                       // wave-uniform
        float v = agg[node * HID + c];
        if (g != curg) {
            if (curg >= 0) {
                atomicAdd(&pooled[curg * HID + c], accv);
                if (c == 0) atomicAdd(&cnt[curg], cntacc);
            }
            curg = g; accv = 0.f; cntacc = 0.f;
        }
        accv += v;
        cntacc += 1.f;
    }
    if (curg >= 0) {
        atomicAdd(&pooled[curg * HID + c], accv);
        if (c == 0) atomicAdd(&cnt[curg], cntacc);
    }
}

// ---------------------------------------------------------------- head
__global__ void k_out(const float* __restrict__ pooled, const float* __restrict__ cnt,
                      const float* __restrict__ Wl, const float* __restrict__ bl,
                      float* __restrict__ out) {
    int tid = threadIdx.x;              // 1024 threads
    int g = tid >> 4, k = tid & 15;
    float inv = 1.0f / fmaxf(cnt[g], 1.0f);
    float acc = 0.f;
#pragma unroll
    for (int h = 0; h < HID; ++h) acc += pooled[g * HID + h] * Wl[h * N_CLASSES + k];
    out[g * N_CLASSES + k] = acc * inv + bl[k];
}

extern "C" void kernel_launch(void* const* d_in, const int* in_sizes, int n_in,
                              void* d_out, int out_size, void* d_ws, size_t ws_size,
                              hipStream_t stream) {
    const float* x     = (const float*)d_in[0];
    const int*   ei    = (const int*)d_in[1];
    const float* ew    = (const float*)d_in[2];
    const int*   batch = (const int*)d_in[3];
    const float* W1    = (const float*)d_in[4];
    const float* b1    = (const float*)d_in[5];
    const float* W2    = (const float*)d_in[6];
    const float* b2    = (const float*)d_in[7];
    const float* Wl    = (const float*)d_in[8];
    const float* bl    = (const float*)d_in[9];

    const int* srcv = ei;            // edge_index[0]
    const int* dstv = ei + N_EDGES;  // edge_index[1]

    // workspace layout (4-byte elements)
    char* wsb = (char*)d_ws;
    float* deg      = (float*)wsb;                     wsb += 100352 * 4;   // dis after k_rsqrt
    int*   count    = (int*)wsb;                       wsb += 100352 * 4;
    int*   rowptr   = (int*)wsb;                       wsb += 100352 * 4;   // N+1 used
    int*   cursor   = (int*)wsb;                       wsb += 100352 * 4;
    int*   bsum     = (int*)wsb;                       wsb += 512 * 4;
    int*   csr_src  = (int*)wsb;                       wsb += N_EDGES * 4;
    float* csr_norm = (float*)wsb;                     wsb += N_EDGES * 4;
    float* h        = (float*)wsb;                     wsb += N_NODES * HID * 4;
    float* agg      = (float*)wsb;                     wsb += N_NODES * HID * 4;
    float* pooled   = (float*)wsb;                     wsb += N_GRAPHS * HID * 4;
    float* cnt      = (float*)wsb;                     wsb += N_GRAPHS * 4;
    float* out      = (float*)d_out;

    // ---- CSR build (shared by both conv layers)
    k_init<<<(N_NODES + 255) / 256, 256, 0, stream>>>(deg, count, pooled, cnt);
    k_degcount<<<(N_EDGES + 255) / 256, 256, 0, stream>>>(dstv, ew, deg, count);
    k_rsqrt<<<(N_NODES + 255) / 256, 256, 0, stream>>>(deg);
    k_scan_local<<<NBLK, 256, 0, stream>>>(count, rowptr, bsum);
    k_scan_bsum<<<1, 512, 0, stream>>>(bsum);
    k_scan_add<<<NBLK, 256, 0, stream>>>(bsum, rowptr, cursor);
    k_fill<<<(N_EDGES + 255) / 256, 256, 0, stream>>>(srcv, dstv, ew, deg,
                                                      cursor, csr_src, csr_norm);

    // ---- layer 1
    k_gemm<IN_CH><<<N_NODES / 16, 256, 0, stream>>>(x, W1, h);
    k_aggregate<<<(N_NODES + 3) / 4, 256, 0, stream>>>(rowptr, csr_src, csr_norm,
                                                       h, deg, b1, agg);
    // ---- layer 2
    k_gemm<HID><<<N_NODES / 16, 256, 0, stream>>>(agg, W2, h);
    k_aggregate<<<(N_NODES + 3) / 4, 256, 0, stream>>>(rowptr, csr_src, csr_norm,
                                                       h, deg, b2, agg);

    // ---- pool + head
    k_pool<<<(N_NODES + 4 * POOL_NPT - 1) / (4 * POOL_NPT), 256, 0, stream>>>(
        agg, batch, pooled, cnt);
    k_out<<<1, N_GRAPHS * N_CLASSES, 0, stream>>>(pooled, cnt, Wl, bl, out);
}

// Round 4
// 640.453 us; speedup vs baseline: 1.6288x; 1.0392x over previous
//
#include <hip/hip_runtime.h>

#define N_NODES   100000
#define N_EDGES   1600000
#define IN_CH     128
#define HID       64
#define N_CLASSES 16
#define N_GRAPHS  64
#define NBLK      ((N_NODES + 255) / 256)   // 391 scan blocks

// ---------------------------------------------------------------- init
__global__ void k_init(int* __restrict__ count, float* __restrict__ pooled,
                       float* __restrict__ cnt) {
    int i = blockIdx.x * 256 + threadIdx.x;
    if (i < N_NODES) count[i] = 0;
    if (i < N_GRAPHS * HID) pooled[i] = 0.0f;
    if (i < N_GRAPHS) cnt[i] = 0.0f;
}

// ---------------------------------------------------------------- edge count (1 atomic/edge)
__global__ void k_count(const int* __restrict__ dst, int* __restrict__ count) {
    int e = blockIdx.x * 256 + threadIdx.x;
    if (e < N_EDGES) atomicAdd(&count[dst[e]], 1);
}

// ---------------------------------------------------------------- hierarchical scan
__global__ void k_scan_local(const int* __restrict__ count, int* __restrict__ rowptr,
                             int* __restrict__ bsum) {
    __shared__ int sm[256];
    const int t = threadIdx.x;
    const int i = blockIdx.x * 256 + t;
    int v = (i < N_NODES) ? count[i] : 0;
    sm[t] = v;
    __syncthreads();
    for (int off = 1; off < 256; off <<= 1) {
        int add = (t >= off) ? sm[t - off] : 0;
        __syncthreads();
        sm[t] += add;
        __syncthreads();
    }
    if (i < N_NODES) rowptr[i] = sm[t] - v;   // exclusive
    if (t == 255) bsum[blockIdx.x] = sm[255];
}

__global__ void k_scan_bsum(int* __restrict__ bsum) {
    __shared__ int sm[512];
    const int t = threadIdx.x;
    int v = (t < NBLK) ? bsum[t] : 0;
    sm[t] = v;
    __syncthreads();
    for (int off = 1; off < 512; off <<= 1) {
        int add = (t >= off) ? sm[t - off] : 0;
        __syncthreads();
        sm[t] += add;
        __syncthreads();
    }
    if (t < NBLK) bsum[t] = sm[t] - v;        // exclusive
}

__global__ void k_scan_add(const int* __restrict__ bsum, int* __restrict__ rowptr,
                           int* __restrict__ cursor) {
    int i = blockIdx.x * 256 + threadIdx.x;
    if (i < N_NODES) {
        int r = rowptr[i] + bsum[i >> 8];
        rowptr[i] = r;
        cursor[i] = r;
    }
    if (i == 0) rowptr[N_NODES] = N_EDGES;
}

// ---------------------------------------------------------------- fill CSR
// one interleaved 8-byte store per edge: {src, ew_bits}
__global__ void k_fill(const int* __restrict__ src, const int* __restrict__ dst,
                       const float* __restrict__ ew, int* __restrict__ cursor,
                       int2* __restrict__ csr) {
    int e = blockIdx.x * 256 + threadIdx.x;
    if (e < N_EDGES) {
        int s = src[e], d = dst[e];
        float w = ew[e];
        int pos = atomicAdd(&cursor[d], 1);
        csr[pos] = make_int2(s, __float_as_int(w));
    }
}

// ---------------------------------------------------------------- deg from CSR
// dis[i] = 1/sqrt(1 + sum of row ew); sequential contiguous reads
__global__ void k_deg(const int* __restrict__ rowptr, const int2* __restrict__ csr,
                      float* __restrict__ dis) {
    int i = blockIdx.x * 256 + threadIdx.x;
    if (i >= N_NODES) return;
    int p = rowptr[i], end = rowptr[i + 1];
    float s = 1.0f;   // self-loop weight
    for (; p < end; ++p) s += __int_as_float(csr[p].y);
    dis[i] = 1.0f / sqrtf(s);
}

// ---------------------------------------------------------------- norm in place
// csr[p].ew <- dis[dst]*ew*dis[src]
__global__ void k_norm(const int* __restrict__ rowptr, const float* __restrict__ dis,
                       int2* __restrict__ csr) {
    int i = blockIdx.x * 256 + threadIdx.x;
    if (i >= N_NODES) return;
    const float dd = dis[i];
    int p = rowptr[i], end = rowptr[i + 1];
    for (; p < end; ++p) {
        int2 v = csr[p];
        csr[p] = make_int2(v.x, __float_as_int(dd * __int_as_float(v.y) * dis[v.x]));
    }
}

// ---------------------------------------------------------------- GEMM
template <int K>
__global__ void k_gemm(const float* __restrict__ x, const float* __restrict__ W,
                       float* __restrict__ h) {
    __shared__ float ws[K * HID];
    __shared__ float xs[16 * K];
    const int tid = threadIdx.x;
    const int col = tid & 63;
    const int rq  = tid >> 6;          // 0..3
    const int rowbase = blockIdx.x * 16;

    for (int i = tid; i < K * HID; i += 256) ws[i] = W[i];
    for (int i = tid; i < 16 * K; i += 256) {
        int r = i / K, k = i % K;
        xs[r * K + k] = x[(rowbase + r) * K + k];
    }
    __syncthreads();

    float a0 = 0.f, a1 = 0.f, a2 = 0.f, a3 = 0.f;
#pragma unroll 16
    for (int k = 0; k < K; ++k) {
        float wv = ws[k * HID + col];
        a0 += xs[(rq     ) * K + k] * wv;
        a1 += xs[(rq +  4) * K + k] * wv;
        a2 += xs[(rq +  8) * K + k] * wv;
        a3 += xs[(rq + 12) * K + k] * wv;
    }
    h[(rowbase + rq     ) * HID + col] = a0;
    h[(rowbase + rq +  4) * HID + col] = a1;
    h[(rowbase + rq +  8) * HID + col] = a2;
    h[(rowbase + rq + 12) * HID + col] = a3;
}

// ---------------------------------------------------------------- aggregate (gather)
// out[i,c] = relu( dis[i]^2*h[i,c] + sum_{p in row} norm[p]*h[src[p],c] + b[c] )
__global__ void k_aggregate(const int* __restrict__ rowptr, const int2* __restrict__ csr,
                            const float* __restrict__ h, const float* __restrict__ dis,
                            const float* __restrict__ b, float* __restrict__ out) {
    const int tid = threadIdx.x;
    const int c = tid & 63;
    const int node = blockIdx.x * 4 + (tid >> 6);
    if (node >= N_NODES) return;
    const float d = dis[node];
    float acc = d * d * h[node * HID + c];
    int p = rowptr[node];
    const int end = rowptr[node + 1];
    for (; p + 2 <= end; p += 2) {
        int2 e0 = csr[p], e1 = csr[p + 1];
        float h0 = h[e0.x * HID + c];
        float h1 = h[e1.x * HID + c];
        acc += __int_as_float(e0.y) * h0;
        acc += __int_as_float(e1.y) * h1;
    }
    if (p < end) {
        int2 e0 = csr[p];
        acc += __int_as_float(e0.y) * h[e0.x * HID + c];
    }
    out[node * HID + c] = fmaxf(acc + b[c], 0.0f);
}

// ---------------------------------------------------------------- pool
#define POOL_NPT 16
__global__ void k_pool(const float* __restrict__ agg, const int* __restrict__ batch,
                       float* __restrict__ pooled, float* __restrict__ cnt) {
    const int tid = threadIdx.x;
    const int c = tid & 63;
    const int rq = tid >> 6;  // 0..3
    const int nodebase = (blockIdx.x * 4 + rq) * POOL_NPT;

    int curg = -1;
    float accv = 0.f, cntacc = 0.f;
    for (int j = 0; j < POOL_NPT; ++j) {
        int node = nodebase + j;
        if (node >= N_NODES) break;
        int g = batch[node];                       // wave-uniform
        float v = agg[node * HID + c];
        if (g != curg) {
            if (curg >= 0) {
                atomicAdd(&pooled[curg * HID + c], accv);
                if (c == 0) atomicAdd(&cnt[curg], cntacc);
            }
            curg = g; accv = 0.f; cntacc = 0.f;
        }
        accv += v;
        cntacc += 1.f;
    }
    if (curg >= 0) {
        atomicAdd(&pooled[curg * HID + c], accv);
        if (c == 0) atomicAdd(&cnt[curg], cntacc);
    }
}

// ---------------------------------------------------------------- head
__global__ void k_out(const float* __restrict__ pooled, const float* __restrict__ cnt,
                      const float* __restrict__ Wl, const float* __restrict__ bl,
                      float* __restrict__ out) {
    int tid = threadIdx.x;              // 1024 threads
    int g = tid >> 4, k = tid & 15;
    float inv = 1.0f / fmaxf(cnt[g], 1.0f);
    float acc = 0.f;
#pragma unroll
    for (int h = 0; h < HID; ++h) acc += pooled[g * HID + h] * Wl[h * N_CLASSES + k];
    out[g * N_CLASSES + k] = acc * inv + bl[k];
}

extern "C" void kernel_launch(void* const* d_in, const int* in_sizes, int n_in,
                              void* d_out, int out_size, void* d_ws, size_t ws_size,
                              hipStream_t stream) {
    const float* x     = (const float*)d_in[0];
    const int*   ei    = (const int*)d_in[1];
    const float* ew    = (const float*)d_in[2];
    const int*   batch = (const int*)d_in[3];
    const float* W1    = (const float*)d_in[4];
    const float* b1    = (const float*)d_in[5];
    const float* W2    = (const float*)d_in[6];
    const float* b2    = (const float*)d_in[7];
    const float* Wl    = (const float*)d_in[8];
    const float* bl    = (const float*)d_in[9];

    const int* srcv = ei;            // edge_index[0]
    const int* dstv = ei + N_EDGES;  // edge_index[1]

    // workspace layout (4-byte elements)
    char* wsb = (char*)d_ws;
    float* dis      = (float*)wsb;                     wsb += 100352 * 4;
    int*   count    = (int*)wsb;                       wsb += 100352 * 4;
    int*   rowptr   = (int*)wsb;                       wsb += 100352 * 4;   // N+1 used
    int*   cursor   = (int*)wsb;                       wsb += 100352 * 4;
    int*   bsum     = (int*)wsb;                       wsb += 512 * 4;
    int2*  csr      = (int2*)wsb;                      wsb += N_EDGES * 8;  // {src, ew/norm}
    float* h        = (float*)wsb;                     wsb += N_NODES * HID * 4;
    float* agg      = (float*)wsb;                     wsb += N_NODES * HID * 4;
    float* pooled   = (float*)wsb;                     wsb += N_GRAPHS * HID * 4;
    float* cnt      = (float*)wsb;                     wsb += N_GRAPHS * 4;
    float* out      = (float*)d_out;

    // ---- CSR build (shared by both conv layers)
    k_init<<<(N_NODES + 255) / 256, 256, 0, stream>>>(count, pooled, cnt);
    k_count<<<(N_EDGES + 255) / 256, 256, 0, stream>>>(dstv, count);
    k_scan_local<<<NBLK, 256, 0, stream>>>(count, rowptr, bsum);
    k_scan_bsum<<<1, 512, 0, stream>>>(bsum);
    k_scan_add<<<NBLK, 256, 0, stream>>>(bsum, rowptr, cursor);
    k_fill<<<(N_EDGES + 255) / 256, 256, 0, stream>>>(srcv, dstv, ew, cursor, csr);
    k_deg<<<NBLK, 256, 0, stream>>>(rowptr, csr, dis);
    k_norm<<<NBLK, 256, 0, stream>>>(rowptr, dis, csr);

    // ---- layer 1
    k_gemm<IN_CH><<<N_NODES / 16, 256, 0, stream>>>(x, W1, h);
    k_aggregate<<<(N_NODES + 3) / 4, 256, 0, stream>>>(rowptr, csr, h, dis, b1, agg);
    // ---- layer 2
    k_gemm<HID><<<N_NODES / 16, 256, 0, stream>>>(agg, W2, h);
    k_aggregate<<<(N_NODES + 3) / 4, 256, 0, stream>>>(rowptr, csr, h, dis, b2, agg);

    // ---- pool + head
    k_pool<<<(N_NODES + 4 * POOL_NPT - 1) / (4 * POOL_NPT), 256, 0, stream>>>(
        agg, batch, pooled, cnt);
    k_out<<<1, N_GRAPHS * N_CLASSES, 0, stream>>>(pooled, cnt, Wl, bl, out);
}

// Round 5
// 499.697 us; speedup vs baseline: 2.0876x; 1.2817x over previous
//
#include <hip/hip_runtime.h>

#define N_NODES   100000
#define N_EDGES   1600000
#define IN_CH     128
#define HID       64
#define N_CLASSES 16
#define N_GRAPHS  64

#define BK_SH     9                          // bucket = dst >> 9 (512 nodes/bucket)
#define BK_NODES  512
#define NB        ((N_NODES + BK_NODES - 1) / BK_NODES)   // 196 buckets
#define CH_EDGES  4096
#define EPT       16                         // edges/thread in binscatter (256 thr)
#define NCH       ((N_EDGES + CH_EDGES - 1) / CH_EDGES)   // 391 chunks

// ---------------------------------------------------------------- init
__global__ void k_init(int* __restrict__ bcount, float* __restrict__ pooled,
                       float* __restrict__ cnt) {
    int i = blockIdx.x * 256 + threadIdx.x;
    if (i < NB) bcount[i] = 0;
    if (i < N_GRAPHS * HID) pooled[i] = 0.0f;
    if (i < N_GRAPHS) cnt[i] = 0.0f;
}

// ---------------------------------------------------------------- bucket histogram
__global__ void k_hist(const int* __restrict__ dst, int* __restrict__ bcount) {
    __shared__ int hist[NB];
    const int t = threadIdx.x;
    for (int i = t; i < NB; i += 256) hist[i] = 0;
    __syncthreads();
    const int base = blockIdx.x * CH_EDGES;
    const int end = min(base + CH_EDGES, N_EDGES);
    for (int i = base + t; i < end; i += 256)
        atomicAdd(&hist[dst[i] >> BK_SH], 1);
    __syncthreads();
    for (int i = t; i < NB; i += 256)
        if (hist[i]) atomicAdd(&bcount[i], hist[i]);
}

// ---------------------------------------------------------------- bucket scan (1 block)
// bbase = exclusive scan of bcount (NB entries, bbase[NB]=E); bcursor = copy
__global__ void k_bscan(const int* __restrict__ bcount, int* __restrict__ bbase,
                        int* __restrict__ bcursor, int* __restrict__ rowptr) {
    __shared__ int sc[256];
    const int t = threadIdx.x;
    int v = (t < NB) ? bcount[t] : 0;
    sc[t] = v;
    __syncthreads();
    for (int off = 1; off < 256; off <<= 1) {
        int a = (t >= off) ? sc[t - off] : 0;
        __syncthreads();
        sc[t] += a;
        __syncthreads();
    }
    if (t < NB) { int e = sc[t] - v; bbase[t] = e; bcursor[t] = e; }
    if (t == 0) { bbase[NB] = N_EDGES; rowptr[N_NODES] = N_EDGES; }
}

// ---------------------------------------------------------------- bin scatter
// stage 4096 edges in LDS sorted by bucket; bulk-reserve per-bucket runs;
// write out mostly-coalesced. bedges entry: {src | dlocal<<17, ew_bits}
__global__ void k_binscatter(const int* __restrict__ src, const int* __restrict__ dst,
                             const float* __restrict__ ew, int* __restrict__ bcursor,
                             int2* __restrict__ bedges) {
    __shared__ int  hist[NB];
    __shared__ int  offs[NB];
    __shared__ int  gbase[NB];
    __shared__ int  sc[256];
    __shared__ int2 stage[CH_EDGES];
    __shared__ int  dest[CH_EDGES];
    const int t = threadIdx.x;
    const int base = blockIdx.x * CH_EDGES;
    const int nloc = min(CH_EDGES, N_EDGES - base);

    for (int i = t; i < NB; i += 256) hist[i] = 0;
    __syncthreads();

    int myb[EPT], myr[EPT], myp[EPT]; float myw[EPT];
#pragma unroll
    for (int j = 0; j < EPT; ++j) {
        int i = base + j * 256 + t;
        if (i < N_EDGES) {
            int s = src[i], d = dst[i];
            int b = d >> BK_SH;
            myb[j] = b;
            myr[j] = atomicAdd(&hist[b], 1);
            myp[j] = s | ((d & (BK_NODES - 1)) << 17);
            myw[j] = ew[i];
        } else {
            myb[j] = -1;
        }
    }
    __syncthreads();

    // exclusive scan of hist (NB <= 256)
    int v = (t < NB) ? hist[t] : 0;
    sc[t] = v;
    __syncthreads();
    for (int off = 1; off < 256; off <<= 1) {
        int a = (t >= off) ? sc[t - off] : 0;
        __syncthreads();
        sc[t] += a;
        __syncthreads();
    }
    if (t < NB) {
        offs[t] = sc[t] - v;
        gbase[t] = (v > 0) ? atomicAdd(&bcursor[t], v) : 0;
    }
    __syncthreads();

#pragma unroll
    for (int j = 0; j < EPT; ++j) {
        if (myb[j] >= 0) {
            int p = offs[myb[j]] + myr[j];
            stage[p] = make_int2(myp[j], __float_as_int(myw[j]));
            dest[p] = gbase[myb[j]] + myr[j];
        }
    }
    __syncthreads();

    for (int i = t; i < nloc; i += 256)
        bedges[dest[i]] = stage[i];
}

// ---------------------------------------------------------------- build CSR per bucket
// one block per bucket: per-node count + weighted degree in LDS, scan, write
// rowptr/dis, then scatter final CSR entries into the block's own region.
__global__ void k_build(const int* __restrict__ bbase, const int2* __restrict__ bedges,
                        int2* __restrict__ csr, int* __restrict__ rowptr,
                        float* __restrict__ dis) {
    __shared__ int   cnt[BK_NODES];
    __shared__ float dsum[BK_NODES];
    __shared__ int   lrp[BK_NODES];
    __shared__ int   cur[BK_NODES];
    __shared__ int   sc[256];
    const int b = blockIdx.x;
    const int t = threadIdx.x;
    const int beg = bbase[b], end = bbase[b + 1];

    for (int i = t; i < BK_NODES; i += 256) { cnt[i] = 0; dsum[i] = 0.0f; }
    __syncthreads();

    for (int i = beg + t; i < end; i += 256) {
        int2 e = bedges[i];
        int dl = ((unsigned)e.x) >> 17;
        atomicAdd(&cnt[dl], 1);
        atomicAdd(&dsum[dl], __int_as_float(e.y));
    }
    __syncthreads();

    // exclusive scan of cnt[512] with 256 threads (2 elements/thread)
    int a0 = cnt[2 * t], a1 = cnt[2 * t + 1];
    int pair = a0 + a1;
    sc[t] = pair;
    __syncthreads();
    for (int off = 1; off < 256; off <<= 1) {
        int a = (t >= off) ? sc[t - off] : 0;
        __syncthreads();
        sc[t] += a;
        __syncthreads();
    }
    int excl = sc[t] - pair;
    lrp[2 * t] = excl;
    lrp[2 * t + 1] = excl + a0;
    cur[2 * t] = excl;
    cur[2 * t + 1] = excl + a0;
    // write rowptr + dis for this bucket's nodes
    {
        int n0 = b * BK_NODES + 2 * t;
        if (n0 < N_NODES) {
            rowptr[n0] = beg + excl;
            dis[n0] = rsqrtf(1.0f + dsum[2 * t]);
        }
        int n1 = n0 + 1;
        if (n1 < N_NODES) {
            rowptr[n1] = beg + excl + a0;
            dis[n1] = rsqrtf(1.0f + dsum[2 * t + 1]);
        }
    }
    __syncthreads();

    // final scatter within this block's contiguous CSR region
    for (int i = beg + t; i < end; i += 256) {
        int2 e = bedges[i];
        int dl = ((unsigned)e.x) >> 17;
        int s = e.x & 0x1FFFF;
        int pos = beg + atomicAdd(&cur[dl], 1);
        csr[pos] = make_int2(s, e.y);
    }
}

// ---------------------------------------------------------------- norm in place
// csr[p].y <- dis[dst]*ew*dis[src]
__global__ void k_norm(const int* __restrict__ rowptr, const float* __restrict__ dis,
                       int2* __restrict__ csr) {
    int i = blockIdx.x * 256 + threadIdx.x;
    if (i >= N_NODES) return;
    const float dd = dis[i];
    int p = rowptr[i], end = rowptr[i + 1];
    for (; p < end; ++p) {
        int2 v = csr[p];
        csr[p] = make_int2(v.x, __float_as_int(dd * __int_as_float(v.y) * dis[v.x]));
    }
}

// ---------------------------------------------------------------- GEMM
template <int K>
__global__ void k_gemm(const float* __restrict__ x, const float* __restrict__ W,
                       float* __restrict__ h) {
    __shared__ float ws[K * HID];
    __shared__ float xs[16 * K];
    const int tid = threadIdx.x;
    const int col = tid & 63;
    const int rq  = tid >> 6;          // 0..3
    const int rowbase = blockIdx.x * 16;

    for (int i = tid; i < K * HID; i += 256) ws[i] = W[i];
    for (int i = tid; i < 16 * K; i += 256) {
        int r = i / K, k = i % K;
        xs[r * K + k] = x[(rowbase + r) * K + k];
    }
    __syncthreads();

    float a0 = 0.f, a1 = 0.f, a2 = 0.f, a3 = 0.f;
#pragma unroll 16
    for (int k = 0; k < K; ++k) {
        float wv = ws[k * HID + col];
        a0 += xs[(rq     ) * K + k] * wv;
        a1 += xs[(rq +  4) * K + k] * wv;
        a2 += xs[(rq +  8) * K + k] * wv;
        a3 += xs[(rq + 12) * K + k] * wv;
    }
    h[(rowbase + rq     ) * HID + col] = a0;
    h[(rowbase + rq +  4) * HID + col] = a1;
    h[(rowbase + rq +  8) * HID + col] = a2;
    h[(rowbase + rq + 12) * HID + col] = a3;
}

// ---------------------------------------------------------------- aggregate (gather)
__global__ void k_aggregate(const int* __restrict__ rowptr, const int2* __restrict__ csr,
                            const float* __restrict__ h, const float* __restrict__ dis,
                            const float* __restrict__ b, float* __restrict__ out) {
    const int tid = threadIdx.x;
    const int c = tid & 63;
    const int node = blockIdx.x * 4 + (tid >> 6);
    if (node >= N_NODES) return;
    const float d = dis[node];
    float acc = d * d * h[node * HID + c];
    int p = rowptr[node];
    const int end = rowptr[node + 1];
    for (; p + 2 <= end; p += 2) {
        int2 e0 = csr[p], e1 = csr[p + 1];
        float h0 = h[e0.x * HID + c];
        float h1 = h[e1.x * HID + c];
        acc += __int_as_float(e0.y) * h0;
        acc += __int_as_float(e1.y) * h1;
    }
    if (p < end) {
        int2 e0 = csr[p];
        acc += __int_as_float(e0.y) * h[e0.x * HID + c];
    }
    out[node * HID + c] = fmaxf(acc + b[c], 0.0f);
}

// ---------------------------------------------------------------- pool
#define POOL_NPT 16
__global__ void k_pool(const float* __restrict__ agg, const int* __restrict__ batch,
                       float* __restrict__ pooled, float* __restrict__ cnt) {
    const int tid = threadIdx.x;
    const int c = tid & 63;
    const int rq = tid >> 6;  // 0..3
    const int nodebase = (blockIdx.x * 4 + rq) * POOL_NPT;

    int curg = -1;
    float accv = 0.f, cntacc = 0.f;
    for (int j = 0; j < POOL_NPT; ++j) {
        int node = nodebase + j;
        if (node >= N_NODES) break;
        int g = batch[node];                       // wave-uniform
        float v = agg[node * HID + c];
        if (g != curg) {
            if (curg >= 0) {
                atomicAdd(&pooled[curg * HID + c], accv);
                if (c == 0) atomicAdd(&cnt[curg], cntacc);
            }
            curg = g; accv = 0.f; cntacc = 0.f;
        }
        accv += v;
        cntacc += 1.f;
    }
    if (curg >= 0) {
        atomicAdd(&pooled[curg * HID + c], accv);
        if (c == 0) atomicAdd(&cnt[curg], cntacc);
    }
}

// ---------------------------------------------------------------- head
__global__ void k_out(const float* __restrict__ pooled, const float* __restrict__ cnt,
                      const float* __restrict__ Wl, const float* __restrict__ bl,
                      float* __restrict__ out) {
    int tid = threadIdx.x;              // 1024 threads
    int g = tid >> 4, k = tid & 15;
    float inv = 1.0f / fmaxf(cnt[g], 1.0f);
    float acc = 0.f;
#pragma unroll
    for (int h = 0; h < HID; ++h) acc += pooled[g * HID + h] * Wl[h * N_CLASSES + k];
    out[g * N_CLASSES + k] = acc * inv + bl[k];
}

extern "C" void kernel_launch(void* const* d_in, const int* in_sizes, int n_in,
                              void* d_out, int out_size, void* d_ws, size_t ws_size,
                              hipStream_t stream) {
    const float* x     = (const float*)d_in[0];
    const int*   ei    = (const int*)d_in[1];
    const float* ew    = (const float*)d_in[2];
    const int*   batch = (const int*)d_in[3];
    const float* W1    = (const float*)d_in[4];
    const float* b1    = (const float*)d_in[5];
    const float* W2    = (const float*)d_in[6];
    const float* b2    = (const float*)d_in[7];
    const float* Wl    = (const float*)d_in[8];
    const float* bl    = (const float*)d_in[9];

    const int* srcv = ei;            // edge_index[0]
    const int* dstv = ei + N_EDGES;  // edge_index[1]

    // workspace layout
    char* wsb = (char*)d_ws;
    float* dis      = (float*)wsb;                     wsb += 100352 * 4;
    int*   rowptr   = (int*)wsb;                       wsb += 100352 * 4;   // N+1 used
    int*   bcount   = (int*)wsb;                       wsb += 256 * 4;
    int*   bbase    = (int*)wsb;                       wsb += 256 * 4;      // NB+1 used
    int*   bcursor  = (int*)wsb;                       wsb += 256 * 4;
    int2*  csr      = (int2*)wsb;                      wsb += N_EDGES * 8;  // {src, ew/norm}
    float* h        = (float*)wsb;                     wsb += N_NODES * HID * 4;
    float* agg      = (float*)wsb;                     wsb += N_NODES * HID * 4;
    float* pooled   = (float*)wsb;                     wsb += N_GRAPHS * HID * 4;
    float* cnt      = (float*)wsb;                     wsb += N_GRAPHS * 4;
    float* out      = (float*)d_out;
    // bedges aliases agg: consumed by k_build before aggregate1 writes agg
    int2*  bedges   = (int2*)agg;

    // ---- CSR build (counting sort, shared by both conv layers)
    k_init<<<(N_NODES + 255) / 256, 256, 0, stream>>>(bcount, pooled, cnt);
    k_hist<<<NCH, 256, 0, stream>>>(dstv, bcount);
    k_bscan<<<1, 256, 0, stream>>>(bcount, bbase, bcursor, rowptr);
    k_binscatter<<<NCH, 256, 0, stream>>>(srcv, dstv, ew, bcursor, bedges);
    k_build<<<NB, 256, 0, stream>>>(bbase, bedges, csr, rowptr, dis);
    k_norm<<<(N_NODES + 255) / 256, 256, 0, stream>>>(rowptr, dis, csr);

    // ---- layer 1
    k_gemm<IN_CH><<<N_NODES / 16, 256, 0, stream>>>(x, W1, h);
    k_aggregate<<<(N_NODES + 3) / 4, 256, 0, stream>>>(rowptr, csr, h, dis, b1, agg);
    // ---- layer 2
    k_gemm<HID><<<N_NODES / 16, 256, 0, stream>>>(agg, W2, h);
    k_aggregate<<<(N_NODES + 3) / 4, 256, 0, stream>>>(rowptr, csr, h, dis, b2, agg);

    // ---- pool + head
    k_pool<<<(N_NODES + 4 * POOL_NPT - 1) / (4 * POOL_NPT), 256, 0, stream>>>(
        agg, batch, pooled, cnt);
    k_out<<<1, N_GRAPHS * N_CLASSES, 0, stream>>>(pooled, cnt, Wl, bl, out);
}

// Round 6
// 438.733 us; speedup vs baseline: 2.3777x; 1.1390x over previous
//
#include <hip/hip_runtime.h>

#define N_NODES   100000
#define N_EDGES   1600000
#define IN_CH     128
#define HID       64
#define N_CLASSES 16
#define N_GRAPHS  64

#define BK_SH     9                          // bucket = dst >> 9 (512 nodes/bucket)
#define BK_NODES  512
#define NB        ((N_NODES + BK_NODES - 1) / BK_NODES)   // 196 buckets
#define CH_EDGES  4096
#define EPT       16                         // edges/thread in binscatter (256 thr)
#define NCH       ((N_EDGES + CH_EDGES - 1) / CH_EDGES)   // 391 chunks

// ---------------------------------------------------------------- init
__global__ void k_init(int* __restrict__ bcount, float* __restrict__ pooled,
                       float* __restrict__ cnt) {
    int i = blockIdx.x * 256 + threadIdx.x;
    if (i < NB) bcount[i] = 0;
    if (i < N_GRAPHS * HID) pooled[i] = 0.0f;
    if (i < N_GRAPHS) cnt[i] = 0.0f;
}

// ---------------------------------------------------------------- bucket histogram
__global__ void k_hist(const int* __restrict__ dst, int* __restrict__ bcount) {
    __shared__ int hist[NB];
    const int t = threadIdx.x;
    for (int i = t; i < NB; i += 256) hist[i] = 0;
    __syncthreads();
    const int base = blockIdx.x * CH_EDGES;
    const int end = min(base + CH_EDGES, N_EDGES);
    for (int i = base + t; i < end; i += 256)
        atomicAdd(&hist[dst[i] >> BK_SH], 1);
    __syncthreads();
    for (int i = t; i < NB; i += 256)
        if (hist[i]) atomicAdd(&bcount[i], hist[i]);
}

// ---------------------------------------------------------------- bucket scan (1 block)
__global__ void k_bscan(const int* __restrict__ bcount, int* __restrict__ bbase,
                        int* __restrict__ bcursor, int* __restrict__ rowptr) {
    __shared__ int sc[256];
    const int t = threadIdx.x;
    int v = (t < NB) ? bcount[t] : 0;
    sc[t] = v;
    __syncthreads();
    for (int off = 1; off < 256; off <<= 1) {
        int a = (t >= off) ? sc[t - off] : 0;
        __syncthreads();
        sc[t] += a;
        __syncthreads();
    }
    if (t < NB) { int e = sc[t] - v; bbase[t] = e; bcursor[t] = e; }
    if (t == 0) { bbase[NB] = N_EDGES; rowptr[N_NODES] = N_EDGES; }
}

// ---------------------------------------------------------------- bin scatter
__global__ void k_binscatter(const int* __restrict__ src, const int* __restrict__ dst,
                             const float* __restrict__ ew, int* __restrict__ bcursor,
                             int2* __restrict__ bedges) {
    __shared__ int  hist[NB];
    __shared__ int  offs[NB];
    __shared__ int  gbase[NB];
    __shared__ int  sc[256];
    __shared__ int2 stage[CH_EDGES];
    __shared__ int  dest[CH_EDGES];
    const int t = threadIdx.x;
    const int base = blockIdx.x * CH_EDGES;
    const int nloc = min(CH_EDGES, N_EDGES - base);

    for (int i = t; i < NB; i += 256) hist[i] = 0;
    __syncthreads();

    int myb[EPT], myr[EPT], myp[EPT]; float myw[EPT];
#pragma unroll
    for (int j = 0; j < EPT; ++j) {
        int i = base + j * 256 + t;
        if (i < N_EDGES) {
            int s = src[i], d = dst[i];
            int b = d >> BK_SH;
            myb[j] = b;
            myr[j] = atomicAdd(&hist[b], 1);
            myp[j] = s | ((d & (BK_NODES - 1)) << 17);
            myw[j] = ew[i];
        } else {
            myb[j] = -1;
        }
    }
    __syncthreads();

    int v = (t < NB) ? hist[t] : 0;
    sc[t] = v;
    __syncthreads();
    for (int off = 1; off < 256; off <<= 1) {
        int a = (t >= off) ? sc[t - off] : 0;
        __syncthreads();
        sc[t] += a;
        __syncthreads();
    }
    if (t < NB) {
        offs[t] = sc[t] - v;
        gbase[t] = (v > 0) ? atomicAdd(&bcursor[t], v) : 0;
    }
    __syncthreads();

#pragma unroll
    for (int j = 0; j < EPT; ++j) {
        if (myb[j] >= 0) {
            int p = offs[myb[j]] + myr[j];
            stage[p] = make_int2(myp[j], __float_as_int(myw[j]));
            dest[p] = gbase[myb[j]] + myr[j];
        }
    }
    __syncthreads();

    for (int i = t; i < nloc; i += 256)
        bedges[dest[i]] = stage[i];
}

// ---------------------------------------------------------------- build CSR per bucket
__global__ void k_build(const int* __restrict__ bbase, const int2* __restrict__ bedges,
                        int2* __restrict__ csr, int* __restrict__ rowptr,
                        float* __restrict__ dis) {
    __shared__ int   cnt[BK_NODES];
    __shared__ float dsum[BK_NODES];
    __shared__ int   cur[BK_NODES];
    __shared__ int   sc[256];
    const int b = blockIdx.x;
    const int t = threadIdx.x;
    const int beg = bbase[b], end = bbase[b + 1];

    for (int i = t; i < BK_NODES; i += 256) { cnt[i] = 0; dsum[i] = 0.0f; }
    __syncthreads();

    for (int i = beg + t; i < end; i += 256) {
        int2 e = bedges[i];
        int dl = ((unsigned)e.x) >> 17;
        atomicAdd(&cnt[dl], 1);
        atomicAdd(&dsum[dl], __int_as_float(e.y));
    }
    __syncthreads();

    int a0 = cnt[2 * t], a1 = cnt[2 * t + 1];
    int pair = a0 + a1;
    sc[t] = pair;
    __syncthreads();
    for (int off = 1; off < 256; off <<= 1) {
        int a = (t >= off) ? sc[t - off] : 0;
        __syncthreads();
        sc[t] += a;
        __syncthreads();
    }
    int excl = sc[t] - pair;
    cur[2 * t] = excl;
    cur[2 * t + 1] = excl + a0;
    {
        int n0 = b * BK_NODES + 2 * t;
        if (n0 < N_NODES) {
            rowptr[n0] = beg + excl;
            dis[n0] = rsqrtf(1.0f + dsum[2 * t]);
        }
        int n1 = n0 + 1;
        if (n1 < N_NODES) {
            rowptr[n1] = beg + excl + a0;
            dis[n1] = rsqrtf(1.0f + dsum[2 * t + 1]);
        }
    }
    __syncthreads();

    for (int i = beg + t; i < end; i += 256) {
        int2 e = bedges[i];
        int dl = ((unsigned)e.x) >> 17;
        int s = e.x & 0x1FFFF;
        int pos = beg + atomicAdd(&cur[dl], 1);
        csr[pos] = make_int2(s, e.y);
    }
}

// ---------------------------------------------------------------- norm in place
__global__ void k_norm(const int* __restrict__ rowptr, const float* __restrict__ dis,
                       int2* __restrict__ csr) {
    int i = blockIdx.x * 256 + threadIdx.x;
    if (i >= N_NODES) return;
    const float dd = dis[i];
    int p = rowptr[i], end = rowptr[i + 1];
    for (; p < end; ++p) {
        int2 v = csr[p];
        csr[p] = make_int2(v.x, __float_as_int(dd * __int_as_float(v.y) * dis[v.x]));
    }
}

// ---------------------------------------------------------------- GEMM
template <int K>
__global__ void k_gemm(const float* __restrict__ x, const float* __restrict__ W,
                       float* __restrict__ h) {
    __shared__ float ws[K * HID];
    __shared__ float xs[16 * K];
    const int tid = threadIdx.x;
    const int col = tid & 63;
    const int rq  = tid >> 6;          // 0..3
    const int rowbase = blockIdx.x * 16;

    for (int i = tid; i < K * HID; i += 256) ws[i] = W[i];
    for (int i = tid; i < 16 * K; i += 256) {
        int r = i / K, k = i % K;
        xs[r * K + k] = x[(rowbase + r) * K + k];
    }
    __syncthreads();

    float a0 = 0.f, a1 = 0.f, a2 = 0.f, a3 = 0.f;
#pragma unroll 16
    for (int k = 0; k < K; ++k) {
        float wv = ws[k * HID + col];
        a0 += xs[(rq     ) * K + k] * wv;
        a1 += xs[(rq +  4) * K + k] * wv;
        a2 += xs[(rq +  8) * K + k] * wv;
        a3 += xs[(rq + 12) * K + k] * wv;
    }
    h[(rowbase + rq     ) * HID + col] = a0;
    h[(rowbase + rq +  4) * HID + col] = a1;
    h[(rowbase + rq +  8) * HID + col] = a2;
    h[(rowbase + rq + 12) * HID + col] = a3;
}

// ---------------------------------------------------------------- aggregate (gather)
// unroll-8: 8 descriptor loads, then 8 independent h-row gathers in flight.
__global__ void k_aggregate(const int* __restrict__ rowptr, const int2* __restrict__ csr,
                            const float* __restrict__ h, const float* __restrict__ dis,
                            const float* __restrict__ b, float* __restrict__ out) {
    const int tid = threadIdx.x;
    const int c = tid & 63;
    const int node = blockIdx.x * 4 + (tid >> 6);
    if (node >= N_NODES) return;
    const float d = dis[node];
    float acc = d * d * h[node * HID + c];
    int p = rowptr[node];
    const int end = rowptr[node + 1];

    while (p + 8 <= end) {
        int2 e0 = csr[p    ], e1 = csr[p + 1], e2 = csr[p + 2], e3 = csr[p + 3];
        int2 e4 = csr[p + 4], e5 = csr[p + 5], e6 = csr[p + 6], e7 = csr[p + 7];
        float h0 = h[e0.x * HID + c];
        float h1 = h[e1.x * HID + c];
        float h2 = h[e2.x * HID + c];
        float h3 = h[e3.x * HID + c];
        float h4 = h[e4.x * HID + c];
        float h5 = h[e5.x * HID + c];
        float h6 = h[e6.x * HID + c];
        float h7 = h[e7.x * HID + c];
        acc += __int_as_float(e0.y) * h0;
        acc += __int_as_float(e1.y) * h1;
        acc += __int_as_float(e2.y) * h2;
        acc += __int_as_float(e3.y) * h3;
        acc += __int_as_float(e4.y) * h4;
        acc += __int_as_float(e5.y) * h5;
        acc += __int_as_float(e6.y) * h6;
        acc += __int_as_float(e7.y) * h7;
        p += 8;
    }
    if (p + 4 <= end) {
        int2 e0 = csr[p], e1 = csr[p + 1], e2 = csr[p + 2], e3 = csr[p + 3];
        float h0 = h[e0.x * HID + c];
        float h1 = h[e1.x * HID + c];
        float h2 = h[e2.x * HID + c];
        float h3 = h[e3.x * HID + c];
        acc += __int_as_float(e0.y) * h0;
        acc += __int_as_float(e1.y) * h1;
        acc += __int_as_float(e2.y) * h2;
        acc += __int_as_float(e3.y) * h3;
        p += 4;
    }
    if (p + 2 <= end) {
        int2 e0 = csr[p], e1 = csr[p + 1];
        float h0 = h[e0.x * HID + c];
        float h1 = h[e1.x * HID + c];
        acc += __int_as_float(e0.y) * h0;
        acc += __int_as_float(e1.y) * h1;
        p += 2;
    }
    if (p < end) {
        int2 e0 = csr[p];
        acc += __int_as_float(e0.y) * h[e0.x * HID + c];
    }
    out[node * HID + c] = fmaxf(acc + b[c], 0.0f);
}

// ---------------------------------------------------------------- pool
#define POOL_NPT 16
__global__ void k_pool(const float* __restrict__ agg, const int* __restrict__ batch,
                       float* __restrict__ pooled, float* __restrict__ cnt) {
    const int tid = threadIdx.x;
    const int c = tid & 63;
    const int rq = tid >> 6;  // 0..3
    const int nodebase = (blockIdx.x * 4 + rq) * POOL_NPT;

    int curg = -1;
    float accv = 0.f, cntacc = 0.f;
    for (int j = 0; j < POOL_NPT; ++j) {
        int node = nodebase + j;
        if (node >= N_NODES) break;
        int g = batch[node];                       // wave-uniform
        float v = agg[node * HID + c];
        if (g != curg) {
            if (curg >= 0) {
                atomicAdd(&pooled[curg * HID + c], accv);
                if (c == 0) atomicAdd(&cnt[curg], cntacc);
            }
            curg = g; accv = 0.f; cntacc = 0.f;
        }
        accv += v;
        cntacc += 1.f;
    }
    if (curg >= 0) {
        atomicAdd(&pooled[curg * HID + c], accv);
        if (c == 0) atomicAdd(&cnt[curg], cntacc);
    }
}

// ---------------------------------------------------------------- head
__global__ void k_out(const float* __restrict__ pooled, const float* __restrict__ cnt,
                      const float* __restrict__ Wl, const float* __restrict__ bl,
                      float* __restrict__ out) {
    int tid = threadIdx.x;              // 1024 threads
    int g = tid >> 4, k = tid & 15;
    float inv = 1.0f / fmaxf(cnt[g], 1.0f);
    float acc = 0.f;
#pragma unroll
    for (int h = 0; h < HID; ++h) acc += pooled[g * HID + h] * Wl[h * N_CLASSES + k];
    out[g * N_CLASSES + k] = acc * inv + bl[k];
}

extern "C" void kernel_launch(void* const* d_in, const int* in_sizes, int n_in,
                              void* d_out, int out_size, void* d_ws, size_t ws_size,
                              hipStream_t stream) {
    const float* x     = (const float*)d_in[0];
    const int*   ei    = (const int*)d_in[1];
    const float* ew    = (const float*)d_in[2];
    const int*   batch = (const int*)d_in[3];
    const float* W1    = (const float*)d_in[4];
    const float* b1    = (const float*)d_in[5];
    const float* W2    = (const float*)d_in[6];
    const float* b2    = (const float*)d_in[7];
    const float* Wl    = (const float*)d_in[8];
    const float* bl    = (const float*)d_in[9];

    const int* srcv = ei;            // edge_index[0]
    const int* dstv = ei + N_EDGES;  // edge_index[1]

    // workspace layout
    char* wsb = (char*)d_ws;
    float* dis      = (float*)wsb;                     wsb += 100352 * 4;
    int*   rowptr   = (int*)wsb;                       wsb += 100352 * 4;   // N+1 used
    int*   bcount   = (int*)wsb;                       wsb += 256 * 4;
    int*   bbase    = (int*)wsb;                       wsb += 256 * 4;      // NB+1 used
    int*   bcursor  = (int*)wsb;                       wsb += 256 * 4;
    int2*  csr      = (int2*)wsb;                      wsb += N_EDGES * 8;  // {src, ew/norm}
    float* h        = (float*)wsb;                     wsb += N_NODES * HID * 4;
    float* agg      = (float*)wsb;                     wsb += N_NODES * HID * 4;
    float* pooled   = (float*)wsb;                     wsb += N_GRAPHS * HID * 4;
    float* cnt      = (float*)wsb;                     wsb += N_GRAPHS * 4;
    float* out      = (float*)d_out;
    int2*  bedges   = (int2*)agg;   // aliases agg; consumed before aggregate1 writes

    // ---- CSR build (counting sort, shared by both conv layers)
    k_init<<<(N_NODES + 255) / 256, 256, 0, stream>>>(bcount, pooled, cnt);
    k_hist<<<NCH, 256, 0, stream>>>(dstv, bcount);
    k_bscan<<<1, 256, 0, stream>>>(bcount, bbase, bcursor, rowptr);
    k_binscatter<<<NCH, 256, 0, stream>>>(srcv, dstv, ew, bcursor, bedges);
    k_build<<<NB, 256, 0, stream>>>(bbase, bedges, csr, rowptr, dis);
    k_norm<<<(N_NODES + 255) / 256, 256, 0, stream>>>(rowptr, dis, csr);

    // ---- layer 1
    k_gemm<IN_CH><<<N_NODES / 16, 256, 0, stream>>>(x, W1, h);
    k_aggregate<<<(N_NODES + 3) / 4, 256, 0, stream>>>(rowptr, csr, h, dis, b1, agg);
    // ---- layer 2
    k_gemm<HID><<<N_NODES / 16, 256, 0, stream>>>(agg, W2, h);
    k_aggregate<<<(N_NODES + 3) / 4, 256, 0, stream>>>(rowptr, csr, h, dis, b2, agg);

    // ---- pool + head
    k_pool<<<(N_NODES + 4 * POOL_NPT - 1) / (4 * POOL_NPT), 256, 0, stream>>>(
        agg, batch, pooled, cnt);
    k_out<<<1, N_GRAPHS * N_CLASSES, 0, stream>>>(pooled, cnt, Wl, bl, out);
}

// Round 7
// 419.825 us; speedup vs baseline: 2.4848x; 1.0450x over previous
//
#include <hip/hip_runtime.h>

#define N_NODES   100000
#define N_EDGES   1600000
#define IN_CH     128
#define HID       64
#define N_CLASSES 16
#define N_GRAPHS  64

#define BK_SH     9                          // bucket = dst >> 9 (512 nodes/bucket)
#define BK_NODES  512
#define NB        ((N_NODES + BK_NODES - 1) / BK_NODES)   // 196 buckets
#define CH_EDGES  4096
#define EPT       16                         // edges/thread in binscatter (256 thr)
#define NCH       ((N_EDGES + CH_EDGES - 1) / CH_EDGES)   // 391 chunks

// ---------------------------------------------------------------- init
__global__ void k_init(int* __restrict__ bcount, float* __restrict__ pooled,
                       float* __restrict__ cnt) {
    int i = blockIdx.x * 256 + threadIdx.x;
    if (i < NB) bcount[i] = 0;
    if (i < N_GRAPHS * HID) pooled[i] = 0.0f;
    if (i < N_GRAPHS) cnt[i] = 0.0f;
}

// ---------------------------------------------------------------- bucket histogram
__global__ void k_hist(const int* __restrict__ dst, int* __restrict__ bcount) {
    __shared__ int hist[NB];
    const int t = threadIdx.x;
    for (int i = t; i < NB; i += 256) hist[i] = 0;
    __syncthreads();
    const int base = blockIdx.x * CH_EDGES;
    const int end = min(base + CH_EDGES, N_EDGES);
    for (int i = base + t; i < end; i += 256)
        atomicAdd(&hist[dst[i] >> BK_SH], 1);
    __syncthreads();
    for (int i = t; i < NB; i += 256)
        if (hist[i]) atomicAdd(&bcount[i], hist[i]);
}

// ---------------------------------------------------------------- bucket scan (1 block)
__global__ void k_bscan(const int* __restrict__ bcount, int* __restrict__ bbase,
                        int* __restrict__ bcursor, int* __restrict__ rowptr) {
    __shared__ int sc[256];
    const int t = threadIdx.x;
    int v = (t < NB) ? bcount[t] : 0;
    sc[t] = v;
    __syncthreads();
    for (int off = 1; off < 256; off <<= 1) {
        int a = (t >= off) ? sc[t - off] : 0;
        __syncthreads();
        sc[t] += a;
        __syncthreads();
    }
    if (t < NB) { int e = sc[t] - v; bbase[t] = e; bcursor[t] = e; }
    if (t == 0) { bbase[NB] = N_EDGES; rowptr[N_NODES] = N_EDGES; }
}

// ---------------------------------------------------------------- bin scatter
__global__ void k_binscatter(const int* __restrict__ src, const int* __restrict__ dst,
                             const float* __restrict__ ew, int* __restrict__ bcursor,
                             int2* __restrict__ bedges) {
    __shared__ int  hist[NB];
    __shared__ int  offs[NB];
    __shared__ int  gbase[NB];
    __shared__ int  sc[256];
    __shared__ int2 stage[CH_EDGES];
    __shared__ int  dest[CH_EDGES];
    const int t = threadIdx.x;
    const int base = blockIdx.x * CH_EDGES;
    const int nloc = min(CH_EDGES, N_EDGES - base);

    for (int i = t; i < NB; i += 256) hist[i] = 0;
    __syncthreads();

    int myb[EPT], myr[EPT], myp[EPT]; float myw[EPT];
#pragma unroll
    for (int j = 0; j < EPT; ++j) {
        int i = base + j * 256 + t;
        if (i < N_EDGES) {
            int s = src[i], d = dst[i];
            int b = d >> BK_SH;
            myb[j] = b;
            myr[j] = atomicAdd(&hist[b], 1);
            myp[j] = s | ((d & (BK_NODES - 1)) << 17);
            myw[j] = ew[i];
        } else {
            myb[j] = -1;
        }
    }
    __syncthreads();

    int v = (t < NB) ? hist[t] : 0;
    sc[t] = v;
    __syncthreads();
    for (int off = 1; off < 256; off <<= 1) {
        int a = (t >= off) ? sc[t - off] : 0;
        __syncthreads();
        sc[t] += a;
        __syncthreads();
    }
    if (t < NB) {
        offs[t] = sc[t] - v;
        gbase[t] = (v > 0) ? atomicAdd(&bcursor[t], v) : 0;
    }
    __syncthreads();

#pragma unroll
    for (int j = 0; j < EPT; ++j) {
        if (myb[j] >= 0) {
            int p = offs[myb[j]] + myr[j];
            stage[p] = make_int2(myp[j], __float_as_int(myw[j]));
            dest[p] = gbase[myb[j]] + myr[j];
        }
    }
    __syncthreads();

    for (int i = t; i < nloc; i += 256)
        bedges[dest[i]] = stage[i];
}

// ---------------------------------------------------------------- build pass 1
// per-bucket: node counts + weighted degree -> rowptr + dis
__global__ void k_build1(const int* __restrict__ bbase, const int2* __restrict__ bedges,
                         int* __restrict__ rowptr, float* __restrict__ dis) {
    __shared__ int   cnt[BK_NODES];
    __shared__ float dsum[BK_NODES];
    __shared__ int   sc[256];
    const int b = blockIdx.x;
    const int t = threadIdx.x;
    const int beg = bbase[b], end = bbase[b + 1];

    for (int i = t; i < BK_NODES; i += 256) { cnt[i] = 0; dsum[i] = 0.0f; }
    __syncthreads();

    for (int i = beg + t; i < end; i += 256) {
        int2 e = bedges[i];
        int dl = ((unsigned)e.x) >> 17;
        atomicAdd(&cnt[dl], 1);
        atomicAdd(&dsum[dl], __int_as_float(e.y));
    }
    __syncthreads();

    int a0 = cnt[2 * t], a1 = cnt[2 * t + 1];
    int pair = a0 + a1;
    sc[t] = pair;
    __syncthreads();
    for (int off = 1; off < 256; off <<= 1) {
        int a = (t >= off) ? sc[t - off] : 0;
        __syncthreads();
        sc[t] += a;
        __syncthreads();
    }
    int excl = sc[t] - pair;
    {
        int n0 = b * BK_NODES + 2 * t;
        if (n0 < N_NODES) {
            rowptr[n0] = beg + excl;
            dis[n0] = rsqrtf(1.0f + dsum[2 * t]);
        }
        int n1 = n0 + 1;
        if (n1 < N_NODES) {
            rowptr[n1] = beg + excl + a0;
            dis[n1] = rsqrtf(1.0f + dsum[2 * t + 1]);
        }
    }
}

// ---------------------------------------------------------------- build pass 2
// per-bucket scatter with norm fused: csr[pos] = {src, dis[dst]*ew*dis[src]}
__global__ void k_build2(const int* __restrict__ bbase, const int2* __restrict__ bedges,
                         const int* __restrict__ rowptr, const float* __restrict__ dis,
                         int2* __restrict__ csr) {
    __shared__ int   cur[BK_NODES];
    __shared__ float ldis[BK_NODES];
    const int b = blockIdx.x;
    const int t = threadIdx.x;
    const int beg = bbase[b], end = bbase[b + 1];
    const int nb = b * BK_NODES;

    for (int i = t; i < BK_NODES; i += 256) {
        int nd = nb + i;
        cur[i]  = (nd < N_NODES) ? rowptr[nd] - beg : 0;
        ldis[i] = (nd < N_NODES) ? dis[nd] : 0.0f;
    }
    __syncthreads();

    for (int i = beg + t; i < end; i += 256) {
        int2 e = bedges[i];
        int dl = ((unsigned)e.x) >> 17;
        int s = e.x & 0x1FFFF;
        float nm = ldis[dl] * __int_as_float(e.y) * dis[s];
        int pos = beg + atomicAdd(&cur[dl], 1);
        csr[pos] = make_int2(s, __float_as_int(nm));
    }
}

// ---------------------------------------------------------------- GEMM
template <int K>
__global__ void k_gemm(const float* __restrict__ x, const float* __restrict__ W,
                       float* __restrict__ h) {
    __shared__ float ws[K * HID];
    __shared__ float xs[16 * K];
    const int tid = threadIdx.x;
    const int col = tid & 63;
    const int rq  = tid >> 6;          // 0..3
    const int rowbase = blockIdx.x * 16;

    for (int i = tid; i < K * HID; i += 256) ws[i] = W[i];
    for (int i = tid; i < 16 * K; i += 256) {
        int r = i / K, k = i % K;
        xs[r * K + k] = x[(rowbase + r) * K + k];
    }
    __syncthreads();

    float a0 = 0.f, a1 = 0.f, a2 = 0.f, a3 = 0.f;
#pragma unroll 16
    for (int k = 0; k < K; ++k) {
        float wv = ws[k * HID + col];
        a0 += xs[(rq     ) * K + k] * wv;
        a1 += xs[(rq +  4) * K + k] * wv;
        a2 += xs[(rq +  8) * K + k] * wv;
        a3 += xs[(rq + 12) * K + k] * wv;
    }
    h[(rowbase + rq     ) * HID + col] = a0;
    h[(rowbase + rq +  4) * HID + col] = a1;
    h[(rowbase + rq +  8) * HID + col] = a2;
    h[(rowbase + rq + 12) * HID + col] = a3;
}

// ---------------------------------------------------------------- aggregate (gather)
// 16-lane float4 groups: one vmem instruction fetches 4 h-rows (64 lanes x 16B).
// 4-deep unroll = 16 rows in flight per wave. Butterfly-reduce groups at the end.
__global__ void k_aggregate(const int* __restrict__ rowptr, const int2* __restrict__ csr,
                            const float4* __restrict__ h4, const float* __restrict__ dis,
                            const float* __restrict__ b, float4* __restrict__ out4) {
    const int tid  = threadIdx.x;
    const int lane = tid & 63;
    const int node = blockIdx.x * 4 + (tid >> 6);
    const int g    = lane >> 4;          // edge group 0..3
    const int c4   = lane & 15;          // float4 channel index
    if (node >= N_NODES) return;

    const float d = dis[node];
    float4 hs = h4[node * 16 + c4];
    float wself = (g == 0) ? d * d : 0.0f;
    float4 acc;
    acc.x = wself * hs.x; acc.y = wself * hs.y;
    acc.z = wself * hs.z; acc.w = wself * hs.w;

    int p = rowptr[node];
    const int end = rowptr[node + 1];

    for (; p + 16 <= end; p += 16) {
        int2 e0 = csr[p + g];
        int2 e1 = csr[p + 4 + g];
        int2 e2 = csr[p + 8 + g];
        int2 e3 = csr[p + 12 + g];
        float4 v0 = h4[e0.x * 16 + c4];
        float4 v1 = h4[e1.x * 16 + c4];
        float4 v2 = h4[e2.x * 16 + c4];
        float4 v3 = h4[e3.x * 16 + c4];
        float w0 = __int_as_float(e0.y), w1 = __int_as_float(e1.y);
        float w2 = __int_as_float(e2.y), w3 = __int_as_float(e3.y);
        acc.x += w0 * v0.x; acc.y += w0 * v0.y; acc.z += w0 * v0.z; acc.w += w0 * v0.w;
        acc.x += w1 * v1.x; acc.y += w1 * v1.y; acc.z += w1 * v1.z; acc.w += w1 * v1.w;
        acc.x += w2 * v2.x; acc.y += w2 * v2.y; acc.z += w2 * v2.z; acc.w += w2 * v2.w;
        acc.x += w3 * v3.x; acc.y += w3 * v3.y; acc.z += w3 * v3.z; acc.w += w3 * v3.w;
    }
    if (p < end) {   // clamped tail block (end-1 >= p)
        int i0 = p + g, i1 = p + 4 + g, i2 = p + 8 + g, i3 = p + 12 + g;
        int2 e0 = csr[min(i0, end - 1)];
        int2 e1 = csr[min(i1, end - 1)];
        int2 e2 = csr[min(i2, end - 1)];
        int2 e3 = csr[min(i3, end - 1)];
        float4 v0 = h4[e0.x * 16 + c4];
        float4 v1 = h4[e1.x * 16 + c4];
        float4 v2 = h4[e2.x * 16 + c4];
        float4 v3 = h4[e3.x * 16 + c4];
        float w0 = (i0 < end) ? __int_as_float(e0.y) : 0.0f;
        float w1 = (i1 < end) ? __int_as_float(e1.y) : 0.0f;
        float w2 = (i2 < end) ? __int_as_float(e2.y) : 0.0f;
        float w3 = (i3 < end) ? __int_as_float(e3.y) : 0.0f;
        acc.x += w0 * v0.x; acc.y += w0 * v0.y; acc.z += w0 * v0.z; acc.w += w0 * v0.w;
        acc.x += w1 * v1.x; acc.y += w1 * v1.y; acc.z += w1 * v1.z; acc.w += w1 * v1.w;
        acc.x += w2 * v2.x; acc.y += w2 * v2.y; acc.z += w2 * v2.z; acc.w += w2 * v2.w;
        acc.x += w3 * v3.x; acc.y += w3 * v3.y; acc.z += w3 * v3.z; acc.w += w3 * v3.w;
    }

    // combine the 4 groups (lanes l, l^16, l^32, l^48 hold partial sums of same channels)
    acc.x += __shfl_xor(acc.x, 16); acc.y += __shfl_xor(acc.y, 16);
    acc.z += __shfl_xor(acc.z, 16); acc.w += __shfl_xor(acc.w, 16);
    acc.x += __shfl_xor(acc.x, 32); acc.y += __shfl_xor(acc.y, 32);
    acc.z += __shfl_xor(acc.z, 32); acc.w += __shfl_xor(acc.w, 32);

    if (g == 0) {
        const float4 bb = ((const float4*)b)[c4];
        float4 o;
        o.x = fmaxf(acc.x + bb.x, 0.0f);
        o.y = fmaxf(acc.y + bb.y, 0.0f);
        o.z = fmaxf(acc.z + bb.z, 0.0f);
        o.w = fmaxf(acc.w + bb.w, 0.0f);
        out4[node * 16 + c4] = o;
    }
}

// ---------------------------------------------------------------- pool
#define POOL_NPT 16
__global__ void k_pool(const float* __restrict__ agg, const int* __restrict__ batch,
                       float* __restrict__ pooled, float* __restrict__ cnt) {
    const int tid = threadIdx.x;
    const int c = tid & 63;
    const int rq = tid >> 6;  // 0..3
    const int nodebase = (blockIdx.x * 4 + rq) * POOL_NPT;

    int curg = -1;
    float accv = 0.f, cntacc = 0.f;
    for (int j = 0; j < POOL_NPT; ++j) {
        int node = nodebase + j;
        if (node >= N_NODES) break;
        int g = batch[node];                       // wave-uniform
        float v = agg[node * HID + c];
        if (g != curg) {
            if (curg >= 0) {
                atomicAdd(&pooled[curg * HID + c], accv);
                if (c == 0) atomicAdd(&cnt[curg], cntacc);
            }
            curg = g; accv = 0.f; cntacc = 0.f;
        }
        accv += v;
        cntacc += 1.f;
    }
    if (curg >= 0) {
        atomicAdd(&pooled[curg * HID + c], accv);
        if (c == 0) atomicAdd(&cnt[curg], cntacc);
    }
}

// ---------------------------------------------------------------- head
__global__ void k_out(const float* __restrict__ pooled, const float* __restrict__ cnt,
                      const float* __restrict__ Wl, const float* __restrict__ bl,
                      float* __restrict__ out) {
    int tid = threadIdx.x;              // 1024 threads
    int g = tid >> 4, k = tid & 15;
    float inv = 1.0f / fmaxf(cnt[g], 1.0f);
    float acc = 0.f;
#pragma unroll
    for (int h = 0; h < HID; ++h) acc += pooled[g * HID + h] * Wl[h * N_CLASSES + k];
    out[g * N_CLASSES + k] = acc * inv + bl[k];
}

extern "C" void kernel_launch(void* const* d_in, const int* in_sizes, int n_in,
                              void* d_out, int out_size, void* d_ws, size_t ws_size,
                              hipStream_t stream) {
    const float* x     = (const float*)d_in[0];
    const int*   ei    = (const int*)d_in[1];
    const float* ew    = (const float*)d_in[2];
    const int*   batch = (const int*)d_in[3];
    const float* W1    = (const float*)d_in[4];
    const float* b1    = (const float*)d_in[5];
    const float* W2    = (const float*)d_in[6];
    const float* b2    = (const float*)d_in[7];
    const float* Wl    = (const float*)d_in[8];
    const float* bl    = (const float*)d_in[9];

    const int* srcv = ei;            // edge_index[0]
    const int* dstv = ei + N_EDGES;  // edge_index[1]

    // workspace layout (all offsets 16B-aligned)
    char* wsb = (char*)d_ws;
    float* dis      = (float*)wsb;                     wsb += 100352 * 4;
    int*   rowptr   = (int*)wsb;                       wsb += 100352 * 4;   // N+1 used
    int*   bcount   = (int*)wsb;                       wsb += 256 * 4;
    int*   bbase    = (int*)wsb;                       wsb += 256 * 4;      // NB+1 used
    int*   bcursor  = (int*)wsb;                       wsb += 256 * 4;
    int2*  csr      = (int2*)wsb;                      wsb += N_EDGES * 8;  // {src, norm}
    float* h        = (float*)wsb;                     wsb += N_NODES * HID * 4;
    float* agg      = (float*)wsb;                     wsb += N_NODES * HID * 4;
    float* pooled   = (float*)wsb;                     wsb += N_GRAPHS * HID * 4;
    float* cnt      = (float*)wsb;                     wsb += N_GRAPHS * 4;
    float* out      = (float*)d_out;
    int2*  bedges   = (int2*)agg;   // aliases agg; consumed in build2 before aggregate1

    // ---- CSR build (counting sort, shared by both conv layers)
    k_init<<<(N_NODES + 255) / 256, 256, 0, stream>>>(bcount, pooled, cnt);
    k_hist<<<NCH, 256, 0, stream>>>(dstv, bcount);
    k_bscan<<<1, 256, 0, stream>>>(bcount, bbase, bcursor, rowptr);
    k_binscatter<<<NCH, 256, 0, stream>>>(srcv, dstv, ew, bcursor, bedges);
    k_build1<<<NB, 256, 0, stream>>>(bbase, bedges, rowptr, dis);
    k_build2<<<NB, 256, 0, stream>>>(bbase, bedges, rowptr, dis, csr);

    // ---- layer 1
    k_gemm<IN_CH><<<N_NODES / 16, 256, 0, stream>>>(x, W1, h);
    k_aggregate<<<(N_NODES + 3) / 4, 256, 0, stream>>>(rowptr, csr, (const float4*)h,
                                                       dis, b1, (float4*)agg);
    // ---- layer 2
    k_gemm<HID><<<N_NODES / 16, 256, 0, stream>>>(agg, W2, h);
    k_aggregate<<<(N_NODES + 3) / 4, 256, 0, stream>>>(rowptr, csr, (const float4*)h,
                                                       dis, b2, (float4*)agg);

    // ---- pool + head
    k_pool<<<(N_NODES + 4 * POOL_NPT - 1) / (4 * POOL_NPT), 256, 0, stream>>>(
        agg, batch, pooled, cnt);
    k_out<<<1, N_GRAPHS * N_CLASSES, 0, stream>>>(pooled, cnt, Wl, bl, out);
}

// Round 8
// 382.698 us; speedup vs baseline: 2.7258x; 1.0970x over previous
//
#include <hip/hip_runtime.h>

#define N_NODES   100000
#define N_EDGES   1600000
#define IN_CH     128
#define HID       64
#define N_CLASSES 16
#define N_GRAPHS  64

#define BK_SH     9                          // bucket = dst >> 9 (512 nodes/bucket)
#define BK_NODES  512
#define NB        ((N_NODES + BK_NODES - 1) / BK_NODES)   // 196 buckets
#define CH_EDGES  4096
#define EPT       16                         // edges/thread in binscatter (256 thr)
#define NCH       ((N_EDGES + CH_EDGES - 1) / CH_EDGES)   // 391 chunks

// ---------------------------------------------------------------- init
__global__ void k_init(int* __restrict__ bcount, float* __restrict__ pooled,
                       float* __restrict__ cnt) {
    int i = blockIdx.x * 256 + threadIdx.x;
    if (i < NB) bcount[i] = 0;
    if (i < N_GRAPHS * HID) pooled[i] = 0.0f;
    if (i < N_GRAPHS) cnt[i] = 0.0f;
}

// ---------------------------------------------------------------- bucket histogram
__global__ void k_hist(const int* __restrict__ dst, int* __restrict__ bcount) {
    __shared__ int hist[NB];
    const int t = threadIdx.x;
    for (int i = t; i < NB; i += 256) hist[i] = 0;
    __syncthreads();
    const int base = blockIdx.x * CH_EDGES;
    const int end = min(base + CH_EDGES, N_EDGES);
    for (int i = base + t; i < end; i += 256)
        atomicAdd(&hist[dst[i] >> BK_SH], 1);
    __syncthreads();
    for (int i = t; i < NB; i += 256)
        if (hist[i]) atomicAdd(&bcount[i], hist[i]);
}

// ---------------------------------------------------------------- bucket scan (1 block)
__global__ void k_bscan(const int* __restrict__ bcount, int* __restrict__ bbase,
                        int* __restrict__ bcursor, int* __restrict__ rowptr) {
    __shared__ int sc[256];
    const int t = threadIdx.x;
    int v = (t < NB) ? bcount[t] : 0;
    sc[t] = v;
    __syncthreads();
    for (int off = 1; off < 256; off <<= 1) {
        int a = (t >= off) ? sc[t - off] : 0;
        __syncthreads();
        sc[t] += a;
        __syncthreads();
    }
    if (t < NB) { int e = sc[t] - v; bbase[t] = e; bcursor[t] = e; }
    if (t == 0) { bbase[NB] = N_EDGES; rowptr[N_NODES] = N_EDGES; }
}

// ---------------------------------------------------------------- bin scatter
__global__ void k_binscatter(const int* __restrict__ src, const int* __restrict__ dst,
                             const float* __restrict__ ew, int* __restrict__ bcursor,
                             int2* __restrict__ bedges) {
    __shared__ int  hist[NB];
    __shared__ int  offs[NB];
    __shared__ int  gbase[NB];
    __shared__ int  sc[256];
    __shared__ int2 stage[CH_EDGES];
    __shared__ int  dest[CH_EDGES];
    const int t = threadIdx.x;
    const int base = blockIdx.x * CH_EDGES;
    const int nloc = min(CH_EDGES, N_EDGES - base);

    for (int i = t; i < NB; i += 256) hist[i] = 0;
    __syncthreads();

    int myb[EPT], myr[EPT], myp[EPT]; float myw[EPT];
#pragma unroll
    for (int j = 0; j < EPT; ++j) {
        int i = base + j * 256 + t;
        if (i < N_EDGES) {
            int s = src[i], d = dst[i];
            int b = d >> BK_SH;
            myb[j] = b;
            myr[j] = atomicAdd(&hist[b], 1);
            myp[j] = s | ((d & (BK_NODES - 1)) << 17);
            myw[j] = ew[i];
        } else {
            myb[j] = -1;
        }
    }
    __syncthreads();

    int v = (t < NB) ? hist[t] : 0;
    sc[t] = v;
    __syncthreads();
    for (int off = 1; off < 256; off <<= 1) {
        int a = (t >= off) ? sc[t - off] : 0;
        __syncthreads();
        sc[t] += a;
        __syncthreads();
    }
    if (t < NB) {
        offs[t] = sc[t] - v;
        gbase[t] = (v > 0) ? atomicAdd(&bcursor[t], v) : 0;
    }
    __syncthreads();

#pragma unroll
    for (int j = 0; j < EPT; ++j) {
        if (myb[j] >= 0) {
            int p = offs[myb[j]] + myr[j];
            stage[p] = make_int2(myp[j], __float_as_int(myw[j]));
            dest[p] = gbase[myb[j]] + myr[j];
        }
    }
    __syncthreads();

    for (int i = t; i < nloc; i += 256)
        bedges[dest[i]] = stage[i];
}

// ---------------------------------------------------------------- build pass 1
__global__ void k_build1(const int* __restrict__ bbase, const int2* __restrict__ bedges,
                         int* __restrict__ rowptr, float* __restrict__ dis) {
    __shared__ int   cnt[BK_NODES];
    __shared__ float dsum[BK_NODES];
    __shared__ int   sc[256];
    const int b = blockIdx.x;
    const int t = threadIdx.x;
    const int beg = bbase[b], end = bbase[b + 1];

    for (int i = t; i < BK_NODES; i += 256) { cnt[i] = 0; dsum[i] = 0.0f; }
    __syncthreads();

    for (int i = beg + t; i < end; i += 256) {
        int2 e = bedges[i];
        int dl = ((unsigned)e.x) >> 17;
        atomicAdd(&cnt[dl], 1);
        atomicAdd(&dsum[dl], __int_as_float(e.y));
    }
    __syncthreads();

    int a0 = cnt[2 * t], a1 = cnt[2 * t + 1];
    int pair = a0 + a1;
    sc[t] = pair;
    __syncthreads();
    for (int off = 1; off < 256; off <<= 1) {
        int a = (t >= off) ? sc[t - off] : 0;
        __syncthreads();
        sc[t] += a;
        __syncthreads();
    }
    int excl = sc[t] - pair;
    {
        int n0 = b * BK_NODES + 2 * t;
        if (n0 < N_NODES) {
            rowptr[n0] = beg + excl;
            dis[n0] = rsqrtf(1.0f + dsum[2 * t]);
        }
        int n1 = n0 + 1;
        if (n1 < N_NODES) {
            rowptr[n1] = beg + excl + a0;
            dis[n1] = rsqrtf(1.0f + dsum[2 * t + 1]);
        }
    }
}

// ---------------------------------------------------------------- build pass 2
__global__ void k_build2(const int* __restrict__ bbase, const int2* __restrict__ bedges,
                         const int* __restrict__ rowptr, const float* __restrict__ dis,
                         int2* __restrict__ csr) {
    __shared__ int   cur[BK_NODES];
    __shared__ float ldis[BK_NODES];
    const int b = blockIdx.x;
    const int t = threadIdx.x;
    const int beg = bbase[b], end = bbase[b + 1];
    const int nb = b * BK_NODES;

    for (int i = t; i < BK_NODES; i += 256) {
        int nd = nb + i;
        cur[i]  = (nd < N_NODES) ? rowptr[nd] - beg : 0;
        ldis[i] = (nd < N_NODES) ? dis[nd] : 0.0f;
    }
    __syncthreads();

    for (int i = beg + t; i < end; i += 256) {
        int2 e = bedges[i];
        int dl = ((unsigned)e.x) >> 17;
        int s = e.x & 0x1FFFF;
        float nm = ldis[dl] * __int_as_float(e.y) * dis[s];
        int pos = beg + atomicAdd(&cur[dl], 1);
        csr[pos] = make_int2(s, __float_as_int(nm));
    }
}

// ---------------------------------------------------------------- GEMM
// 64 rows x 64 cols per block, 256 threads, 4x4 register micro-tile,
// K-tiles of 64. A staged with padded stride 68 (16B-aligned, low-conflict).
template <int K>
__global__ __launch_bounds__(256) void k_gemm(const float* __restrict__ x,
                                              const float* __restrict__ W,
                                              float* __restrict__ h) {
    constexpr int AS = 68;               // padded A row stride (words)
    __shared__ float a_s[64 * AS];       // a_s[row][kk]
    __shared__ float w_s[64 * 64];       // w_s[kk][col]
    const int t  = threadIdx.x;
    const int tx = t & 15;               // output col group
    const int ty = t >> 4;               // output row group
    const int rowbase = blockIdx.x * 64;

    float acc[4][4] = {{0.f}};

    for (int kt = 0; kt < K; kt += 64) {
        // stage A: 64 rows x 64 k; thread (ty,tx): rows ty+16j, k tx*4..+3
#pragma unroll
        for (int j = 0; j < 4; ++j) {
            int row = ty + j * 16;
            int gr = rowbase + row;
            float4 v = (gr < N_NODES)
                ? *(const float4*)&x[(long)gr * K + kt + tx * 4]
                : make_float4(0.f, 0.f, 0.f, 0.f);
            *(float4*)&a_s[row * AS + tx * 4] = v;
        }
        // stage W: w_s[kk][col] = W[(kt+kk)*HID + col]
#pragma unroll
        for (int j = 0; j < 4; ++j) {
            int kk = ty + j * 16;
            *(float4*)&w_s[kk * 64 + tx * 4] =
                *(const float4*)&W[(long)(kt + kk) * HID + tx * 4];
        }
        __syncthreads();

#pragma unroll 8
        for (int kk = 0; kk < 64; ++kk) {
            float4 wv = *(const float4*)&w_s[kk * 64 + tx * 4];
            float a0 = a_s[(ty * 4 + 0) * AS + kk];
            float a1 = a_s[(ty * 4 + 1) * AS + kk];
            float a2 = a_s[(ty * 4 + 2) * AS + kk];
            float a3 = a_s[(ty * 4 + 3) * AS + kk];
            acc[0][0] += a0 * wv.x; acc[0][1] += a0 * wv.y;
            acc[0][2] += a0 * wv.z; acc[0][3] += a0 * wv.w;
            acc[1][0] += a1 * wv.x; acc[1][1] += a1 * wv.y;
            acc[1][2] += a1 * wv.z; acc[1][3] += a1 * wv.w;
            acc[2][0] += a2 * wv.x; acc[2][1] += a2 * wv.y;
            acc[2][2] += a2 * wv.z; acc[2][3] += a2 * wv.w;
            acc[3][0] += a3 * wv.x; acc[3][1] += a3 * wv.y;
            acc[3][2] += a3 * wv.z; acc[3][3] += a3 * wv.w;
        }
        __syncthreads();
    }

#pragma unroll
    for (int i = 0; i < 4; ++i) {
        int gr = rowbase + ty * 4 + i;
        if (gr < N_NODES)
            *(float4*)&h[(long)gr * HID + tx * 4] =
                make_float4(acc[i][0], acc[i][1], acc[i][2], acc[i][3]);
    }
}

// ---------------------------------------------------------------- aggregate (gather)
// 16-lane float4 groups + software-pipelined descriptor prefetch.
__global__ void k_aggregate(const int* __restrict__ rowptr, const int2* __restrict__ csr,
                            const float4* __restrict__ h4, const float* __restrict__ dis,
                            const float* __restrict__ b, float4* __restrict__ out4) {
    const int tid  = threadIdx.x;
    const int lane = tid & 63;
    const int node = blockIdx.x * 4 + (tid >> 6);
    const int g    = lane >> 4;          // edge group 0..3
    const int c4   = lane & 15;          // float4 channel index
    if (node >= N_NODES) return;

    const float d = dis[node];
    float4 hs = h4[node * 16 + c4];
    float wself = (g == 0) ? d * d : 0.0f;
    float4 acc;
    acc.x = wself * hs.x; acc.y = wself * hs.y;
    acc.z = wself * hs.z; acc.w = wself * hs.w;

    int p = rowptr[node];
    const int end = rowptr[node + 1];

    int2 d0, d1, d2, d3;
    if (p + 16 <= end) {
        d0 = csr[p + g];     d1 = csr[p + 4 + g];
        d2 = csr[p + 8 + g]; d3 = csr[p + 12 + g];
    }
    while (p + 16 <= end) {
        const int2 e0 = d0, e1 = d1, e2 = d2, e3 = d3;
        const int pn = p + 16;
        if (pn + 16 <= end) {          // prefetch next batch's descriptors
            d0 = csr[pn + g];     d1 = csr[pn + 4 + g];
            d2 = csr[pn + 8 + g]; d3 = csr[pn + 12 + g];
        }
        float4 v0 = h4[e0.x * 16 + c4];
        float4 v1 = h4[e1.x * 16 + c4];
        float4 v2 = h4[e2.x * 16 + c4];
        float4 v3 = h4[e3.x * 16 + c4];
        float w0 = __int_as_float(e0.y), w1 = __int_as_float(e1.y);
        float w2 = __int_as_float(e2.y), w3 = __int_as_float(e3.y);
        acc.x += w0 * v0.x; acc.y += w0 * v0.y; acc.z += w0 * v0.z; acc.w += w0 * v0.w;
        acc.x += w1 * v1.x; acc.y += w1 * v1.y; acc.z += w1 * v1.z; acc.w += w1 * v1.w;
        acc.x += w2 * v2.x; acc.y += w2 * v2.y; acc.z += w2 * v2.z; acc.w += w2 * v2.w;
        acc.x += w3 * v3.x; acc.y += w3 * v3.y; acc.z += w3 * v3.z; acc.w += w3 * v3.w;
        p = pn;
    }
    if (p < end) {   // clamped tail block
        int i0 = p + g, i1 = p + 4 + g, i2 = p + 8 + g, i3 = p + 12 + g;
        int2 e0 = csr[min(i0, end - 1)];
        int2 e1 = csr[min(i1, end - 1)];
        int2 e2 = csr[min(i2, end - 1)];
        int2 e3 = csr[min(i3, end - 1)];
        float4 v0 = h4[e0.x * 16 + c4];
        float4 v1 = h4[e1.x * 16 + c4];
        float4 v2 = h4[e2.x * 16 + c4];
        float4 v3 = h4[e3.x * 16 + c4];
        float w0 = (i0 < end) ? __int_as_float(e0.y) : 0.0f;
        float w1 = (i1 < end) ? __int_as_float(e1.y) : 0.0f;
        float w2 = (i2 < end) ? __int_as_float(e2.y) : 0.0f;
        float w3 = (i3 < end) ? __int_as_float(e3.y) : 0.0f;
        acc.x += w0 * v0.x; acc.y += w0 * v0.y; acc.z += w0 * v0.z; acc.w += w0 * v0.w;
        acc.x += w1 * v1.x; acc.y += w1 * v1.y; acc.z += w1 * v1.z; acc.w += w1 * v1.w;
        acc.x += w2 * v2.x; acc.y += w2 * v2.y; acc.z += w2 * v2.z; acc.w += w2 * v2.w;
        acc.x += w3 * v3.x; acc.y += w3 * v3.y; acc.z += w3 * v3.z; acc.w += w3 * v3.w;
    }

    acc.x += __shfl_xor(acc.x, 16); acc.y += __shfl_xor(acc.y, 16);
    acc.z += __shfl_xor(acc.z, 16); acc.w += __shfl_xor(acc.w, 16);
    acc.x += __shfl_xor(acc.x, 32); acc.y += __shfl_xor(acc.y, 32);
    acc.z += __shfl_xor(acc.z, 32); acc.w += __shfl_xor(acc.w, 32);

    if (g == 0) {
        const float4 bb = ((const float4*)b)[c4];
        float4 o;
        o.x = fmaxf(acc.x + bb.x, 0.0f);
        o.y = fmaxf(acc.y + bb.y, 0.0f);
        o.z = fmaxf(acc.z + bb.z, 0.0f);
        o.w = fmaxf(acc.w + bb.w, 0.0f);
        out4[node * 16 + c4] = o;
    }
}

// ---------------------------------------------------------------- pool
#define POOL_NPT 16
__global__ void k_pool(const float* __restrict__ agg, const int* __restrict__ batch,
                       float* __restrict__ pooled, float* __restrict__ cnt) {
    const int tid = threadIdx.x;
    const int c = tid & 63;
    const int rq = tid >> 6;  // 0..3
    const int nodebase = (blockIdx.x * 4 + rq) * POOL_NPT;

    int curg = -1;
    float accv = 0.f, cntacc = 0.f;
    for (int j = 0; j < POOL_NPT; ++j) {
        int node = nodebase + j;
        if (node >= N_NODES) break;
        int g = batch[node];                       // wave-uniform
        float v = agg[node * HID + c];
        if (g != curg) {
            if (curg >= 0) {
                atomicAdd(&pooled[curg * HID + c], accv);
                if (c == 0) atomicAdd(&cnt[curg], cntacc);
            }
            curg = g; accv = 0.f; cntacc = 0.f;
        }
        accv += v;
        cntacc += 1.f;
    }
    if (curg >= 0) {
        atomicAdd(&pooled[curg * HID + c], accv);
        if (c == 0) atomicAdd(&cnt[curg], cntacc);
    }
}

// ---------------------------------------------------------------- head
__global__ void k_out(const float* __restrict__ pooled, const float* __restrict__ cnt,
                      const float* __restrict__ Wl, const float* __restrict__ bl,
                      float* __restrict__ out) {
    int tid = threadIdx.x;              // 1024 threads
    int g = tid >> 4, k = tid & 15;
    float inv = 1.0f / fmaxf(cnt[g], 1.0f);
    float acc = 0.f;
#pragma unroll
    for (int h = 0; h < HID; ++h) acc += pooled[g * HID + h] * Wl[h * N_CLASSES + k];
    out[g * N_CLASSES + k] = acc * inv + bl[k];
}

extern "C" void kernel_launch(void* const* d_in, const int* in_sizes, int n_in,
                              void* d_out, int out_size, void* d_ws, size_t ws_size,
                              hipStream_t stream) {
    const float* x     = (const float*)d_in[0];
    const int*   ei    = (const int*)d_in[1];
    const float* ew    = (const float*)d_in[2];
    const int*   batch = (const int*)d_in[3];
    const float* W1    = (const float*)d_in[4];
    const float* b1    = (const float*)d_in[5];
    const float* W2    = (const float*)d_in[6];
    const float* b2    = (const float*)d_in[7];
    const float* Wl    = (const float*)d_in[8];
    const float* bl    = (const float*)d_in[9];

    const int* srcv = ei;            // edge_index[0]
    const int* dstv = ei + N_EDGES;  // edge_index[1]

    // workspace layout (all offsets 16B-aligned)
    char* wsb = (char*)d_ws;
    float* dis      = (float*)wsb;                     wsb += 100352 * 4;
    int*   rowptr   = (int*)wsb;                       wsb += 100352 * 4;   // N+1 used
    int*   bcount   = (int*)wsb;                       wsb += 256 * 4;
    int*   bbase    = (int*)wsb;                       wsb += 256 * 4;      // NB+1 used
    int*   bcursor  = (int*)wsb;                       wsb += 256 * 4;
    int2*  csr      = (int2*)wsb;                      wsb += N_EDGES * 8;  // {src, norm}
    float* h        = (float*)wsb;                     wsb += N_NODES * HID * 4;
    float* agg      = (float*)wsb;                     wsb += N_NODES * HID * 4;
    float* pooled   = (float*)wsb;                     wsb += N_GRAPHS * HID * 4;
    float* cnt      = (float*)wsb;                     wsb += N_GRAPHS * 4;
    float* out      = (float*)d_out;
    int2*  bedges   = (int2*)agg;   // aliases agg; consumed in build2 before aggregate1

    // ---- CSR build (counting sort, shared by both conv layers)
    k_init<<<(N_NODES + 255) / 256, 256, 0, stream>>>(bcount, pooled, cnt);
    k_hist<<<NCH, 256, 0, stream>>>(dstv, bcount);
    k_bscan<<<1, 256, 0, stream>>>(bcount, bbase, bcursor, rowptr);
    k_binscatter<<<NCH, 256, 0, stream>>>(srcv, dstv, ew, bcursor, bedges);
    k_build1<<<NB, 256, 0, stream>>>(bbase, bedges, rowptr, dis);
    k_build2<<<NB, 256, 0, stream>>>(bbase, bedges, rowptr, dis, csr);

    // ---- layer 1
    k_gemm<IN_CH><<<(N_NODES + 63) / 64, 256, 0, stream>>>(x, W1, h);
    k_aggregate<<<(N_NODES + 3) / 4, 256, 0, stream>>>(rowptr, csr, (const float4*)h,
                                                       dis, b1, (float4*)agg);
    // ---- layer 2
    k_gemm<HID><<<(N_NODES + 63) / 64, 256, 0, stream>>>(agg, W2, h);
    k_aggregate<<<(N_NODES + 3) / 4, 256, 0, stream>>>(rowptr, csr, (const float4*)h,
                                                       dis, b2, (float4*)agg);

    // ---- pool + head
    k_pool<<<(N_NODES + 4 * POOL_NPT - 1) / (4 * POOL_NPT), 256, 0, stream>>>(
        agg, batch, pooled, cnt);
    k_out<<<1, N_GRAPHS * N_CLASSES, 0, stream>>>(pooled, cnt, Wl, bl, out);
}